// Round 5
// baseline (1377.254 us; speedup 1.0000x reference)
//
#include <hip/hip_runtime.h>
#include <math.h>

#define NTOT 32768
#define DMODEL 768
#define BSZ 128
#define NHEAD 16
#define DH 48
#define BETA 0.25f

typedef _Float16 f16;
typedef f16 f16x8 __attribute__((ext_vector_type(8)));
typedef f16 f16x4 __attribute__((ext_vector_type(4)));
typedef float f32x4 __attribute__((ext_vector_type(4)));

// ---------------------------------------------------------------------------
// Row stats: mean, rstd (LN, biased var, eps=1e-5), optional l2inv of raw row.
// ---------------------------------------------------------------------------
__global__ __launch_bounds__(256)
void row_stats(const float* __restrict__ X, int M, float* __restrict__ mean,
               float* __restrict__ rstd, float* __restrict__ l2inv) {
  const int row = blockIdx.x * 4 + (threadIdx.x >> 6);
  const int lane = threadIdx.x & 63;
  if (row >= M) return;
  const float* x = X + (size_t)row * DMODEL;
  float s = 0.f, s2 = 0.f;
  for (int i = lane; i < DMODEL; i += 64) {
    float v = x[i];
    s += v; s2 += v * v;
  }
#pragma unroll
  for (int off = 32; off; off >>= 1) {
    s  += __shfl_xor(s, off);
    s2 += __shfl_xor(s2, off);
  }
  if (lane == 0) {
    float mu = s * (1.f / DMODEL);
    float var = s2 * (1.f / DMODEL) - mu * mu;
    mean[row] = mu;
    rstd[row] = rsqrtf(var + 1e-5f);
    if (l2inv) l2inv[row] = 1.f / fmaxf(sqrtf(s2), 1e-12f);
  }
}

// ---------------------------------------------------------------------------
// Fused: stats over mb row + nh = (mb-mu)*rstd f16 hi/lo + logits fold consts.
// ---------------------------------------------------------------------------
__global__ __launch_bounds__(256)
void stats_norm_mb(const float* __restrict__ mb, f16* __restrict__ nh_hi,
                   f16* __restrict__ nh_lo, float* __restrict__ c1,
                   float* __restrict__ c2) {
  const int row = blockIdx.x * 4 + (threadIdx.x >> 6);
  const int lane = threadIdx.x & 63;
  const float* x = mb + (size_t)row * DMODEL;
  float v[12];
  float s = 0.f, s2 = 0.f;
#pragma unroll
  for (int j = 0; j < 3; j++) {
    const float4 v4 = *(const float4*)(x + lane * 4 + j * 256);
    v[j * 4 + 0] = v4.x; v[j * 4 + 1] = v4.y;
    v[j * 4 + 2] = v4.z; v[j * 4 + 3] = v4.w;
    s += v4.x + v4.y + v4.z + v4.w;
    s2 += v4.x * v4.x + v4.y * v4.y + v4.z * v4.z + v4.w * v4.w;
  }
#pragma unroll
  for (int off = 32; off; off >>= 1) {
    s  += __shfl_xor(s, off);
    s2 += __shfl_xor(s2, off);
  }
  const float mu = s * (1.f / DMODEL);
  const float var = s2 * (1.f / DMODEL) - mu * mu;
  const float istd = sqrtf(var + 1e-5f);
  const float rs = 1.f / istd;
  f16* oh = nh_hi + (size_t)row * DMODEL;
  f16* ol = nh_lo + (size_t)row * DMODEL;
#pragma unroll
  for (int j = 0; j < 3; j++) {
    f16x4 h4, l4;
#pragma unroll
    for (int q = 0; q < 4; q++) {
      const float sv = (v[j * 4 + q] - mu) * rs;
      const f16 h = (f16)sv;
      h4[q] = h;
      l4[q] = (f16)(sv - (float)h);
    }
    *(f16x4*)(oh + lane * 4 + j * 256) = h4;
    *(f16x4*)(ol + lane * 4 + j * 256) = l4;
  }
  if (lane == 0) {
    const float l2i = 1.f / fmaxf(sqrtf(s2), 1e-12f);
    c1[row] = 20.f * l2i * istd;
    c2[row] = 20.f * l2i * mu;
  }
}

// ---------------------------------------------------------------------------
// rq_prep: per-row sum, l2inv, and f16 hi/lo split of rq (128 rows).
// ---------------------------------------------------------------------------
__global__ __launch_bounds__(256)
void rq_prep(const float* __restrict__ rq, f16* __restrict__ hi,
             f16* __restrict__ lo, float* __restrict__ ainv,
             float* __restrict__ rqsum) {
  const int row = blockIdx.x * 4 + (threadIdx.x >> 6);
  const int lane = threadIdx.x & 63;
  const float* x = rq + (size_t)row * DMODEL;
  f16* oh = hi + (size_t)row * DMODEL;
  f16* ol = lo + (size_t)row * DMODEL;
  float s = 0.f, s2 = 0.f;
#pragma unroll
  for (int j = 0; j < 3; j++) {
    const int d = lane * 4 + j * 256;
    const float4 v4 = *(const float4*)(x + d);
    const float vv[4] = {v4.x, v4.y, v4.z, v4.w};
    f16x4 h4, l4;
#pragma unroll
    for (int q = 0; q < 4; q++) {
      s += vv[q]; s2 += vv[q] * vv[q];
      const f16 h = (f16)vv[q];
      h4[q] = h;
      l4[q] = (f16)(vv[q] - (float)h);
    }
    *(f16x4*)(oh + d) = h4;
    *(f16x4*)(ol + d) = l4;
  }
#pragma unroll
  for (int off = 32; off; off >>= 1) {
    s  += __shfl_xor(s, off);
    s2 += __shfl_xor(s2, off);
  }
  if (lane == 0) {
    rqsum[row] = s;
    ainv[row] = 1.f / fmaxf(sqrtf(s2), 1e-12f);
  }
}

// ---------------------------------------------------------------------------
// prep_w: combined W' (o<768: g_k*Wk rows; o>=768: g_v*Wv rows), scaled x16,
// split fp16 hi/lo; biasc[o] = bias[o] + sum_d bln[d]*W[o,d].
// ---------------------------------------------------------------------------
__global__ __launch_bounds__(256)
void prep_w(const float* __restrict__ Wk, const float* __restrict__ bk,
            const float* __restrict__ gk, const float* __restrict__ blnk,
            const float* __restrict__ Wv, const float* __restrict__ bv,
            const float* __restrict__ gv, const float* __restrict__ blnv,
            f16* __restrict__ Wc_hi, f16* __restrict__ Wc_lo,
            float* __restrict__ biasc) {
  const int o = blockIdx.x * 4 + (threadIdx.x >> 6);  // 0..1535
  const int lane = threadIdx.x & 63;
  const bool isK = o < DMODEL;
  const float* W = isK ? (Wk + (size_t)o * DMODEL)
                       : (Wv + (size_t)(o - DMODEL) * DMODEL);
  const float* g   = isK ? gk : gv;
  const float* bln = isK ? blnk : blnv;
  float bacc = 0.f;
  for (int d = lane * 4; d < DMODEL; d += 256) {
    const float4 wv = *(const float4*)(W + d);
    const float4 g4 = *(const float4*)(g + d);
    const float4 b4 = *(const float4*)(bln + d);
    bacc += wv.x * b4.x + wv.y * b4.y + wv.z * b4.z + wv.w * b4.w;
    const float sv[4] = {wv.x * g4.x * 16.f, wv.y * g4.y * 16.f,
                         wv.z * g4.z * 16.f, wv.w * g4.w * 16.f};
    f16x4 h4, l4;
#pragma unroll
    for (int j = 0; j < 4; j++) {
      const f16 h = (f16)sv[j];
      h4[j] = h;
      l4[j] = (f16)(sv[j] - (float)h);
    }
    *(f16x4*)(Wc_hi + (size_t)o * DMODEL + d) = h4;
    *(f16x4*)(Wc_lo + (size_t)o * DMODEL + d) = l4;
  }
#pragma unroll
  for (int off = 32; off; off >>= 1) bacc += __shfl_xor(bacc, off);
  if (lane == 0) biasc[o] = (isK ? bk[o] : bv[o - DMODEL]) + bacc;
}

// ---------------------------------------------------------------------------
// Half-projection GEMM via 16x16x32 f16 MFMA, 3-term hi/lo split.
// XCD-aware block swizzle (grid 1536 = 8x192, bijective): same-XCD blocks
// share the nh A-panel in that XCD's L2.
// ---------------------------------------------------------------------------
__global__ __launch_bounds__(256)
void proj_mfma(const f16* __restrict__ nh_hi, const f16* __restrict__ nh_lo,
               const f16* __restrict__ Wc_hi, const f16* __restrict__ Wc_lo,
               const float* __restrict__ biasc,
               f16* __restrict__ k_hi, f16* __restrict__ k_lo,
               f16* __restrict__ T_hi, f16* __restrict__ T_lo, int oc0) {
  __shared__ __align__(16) f16 As[128][64];  // [m][hi/lo-interleaved k]
  __shared__ __align__(16) f16 Bs[128][64];  // [o][...]
  const int t = threadIdx.x;
  // XCD swizzle: dispatch id -> logical block (chunked per XCD)
  const int nwg = gridDim.x * gridDim.y;                       // 1536 (8 | nwg)
  const int bid = blockIdx.x + blockIdx.y * gridDim.x;
  const int swz = (bid & 7) * (nwg >> 3) + (bid >> 3);
  const int bx = swz % gridDim.x, by = swz / gridDim.x;
  const int n0 = oc0 + bx * 128;  // global combined o base
  const int m0 = by * 128;
  const int w = t >> 6, lane = t & 63;
  const int l15 = lane & 15, lq = lane >> 4;
  const int wm = w >> 1, wn = w & 1;
  const int sc = (lane & 7) ^ (lane >> 3);
  const int srow = lane >> 3;

  f32x4 acc[4][4];  // [fo][fm]
#pragma unroll
  for (int a = 0; a < 4; a++)
#pragma unroll
    for (int b = 0; b < 4; b++)
#pragma unroll
      for (int r = 0; r < 4; r++) acc[a][b][r] = 0.f;

  for (int k0 = 0; k0 < DMODEL; k0 += 32) {
    __syncthreads();
#pragma unroll
    for (int i = 0; i < 4; i++) {
      const int rb = (w * 4 + i) * 8;
      const f16* asrc = ((sc < 4) ? nh_hi : nh_lo) +
          (size_t)(m0 + rb + srow) * DMODEL + k0 + (sc & 3) * 8;
      __builtin_amdgcn_global_load_lds(
          (__attribute__((address_space(1))) void*)asrc,
          (__attribute__((address_space(3))) void*)&As[rb][0], 16, 0, 0);
      const f16* bsrc = ((sc < 4) ? Wc_hi : Wc_lo) +
          (size_t)(n0 + rb + srow) * DMODEL + k0 + (sc & 3) * 8;
      __builtin_amdgcn_global_load_lds(
          (__attribute__((address_space(1))) void*)bsrc,
          (__attribute__((address_space(3))) void*)&Bs[rb][0], 16, 0, 0);
    }
    __syncthreads();

    f16x8 nhh[4], nhl[4];  // nh (B operand), free = m
#pragma unroll
    for (int fm = 0; fm < 4; fm++) {
      const int row = wm * 64 + fm * 16 + l15;
      const int e = row & 7;
      nhh[fm] = *(const f16x8*)&As[row][(lq ^ e) * 8];
      nhl[fm] = *(const f16x8*)&As[row][((lq + 4) ^ e) * 8];
    }
    f16x8 wh[4], wl[4];  // W' (A operand), free = o
#pragma unroll
    for (int fo = 0; fo < 4; fo++) {
      const int row = wn * 64 + fo * 16 + l15;
      const int e = row & 7;
      wh[fo] = *(const f16x8*)&Bs[row][(lq ^ e) * 8];
      wl[fo] = *(const f16x8*)&Bs[row][((lq + 4) ^ e) * 8];
    }
#pragma unroll
    for (int fo = 0; fo < 4; fo++)
#pragma unroll
      for (int fm = 0; fm < 4; fm++) {
        f32x4 a = acc[fo][fm];
        a = __builtin_amdgcn_mfma_f32_16x16x32_f16(wh[fo], nhh[fm], a, 0, 0, 0);
        a = __builtin_amdgcn_mfma_f32_16x16x32_f16(wh[fo], nhl[fm], a, 0, 0, 0);
        a = __builtin_amdgcn_mfma_f32_16x16x32_f16(wl[fo], nhh[fm], a, 0, 0, 0);
        acc[fo][fm] = a;
      }
  }
  // --- epilogue: /16, +bias, split hi/lo; transposed always, row-major if K ---
  const int oc = n0 + wn * 64;           // global combined o
  const int obase = (oc - oc0) + lq * 4; // local o (0..767)
  const bool wantRow = (oc0 == 0);
#pragma unroll
  for (int fo = 0; fo < 4; fo++) {
    const float4 bb = *(const float4*)(biasc + oc + fo * 16 + lq * 4);
    const float bbv[4] = {bb.x, bb.y, bb.z, bb.w};
    const int o = obase + fo * 16;
#pragma unroll
    for (int fm = 0; fm < 4; fm++) {
      const int mrow = m0 + wm * 64 + fm * 16 + l15;
      f16x4 h4, l4;
#pragma unroll
      for (int r = 0; r < 4; r++) {
        const float v = acc[fo][fm][r] * 0.0625f + bbv[r];
        const f16 h = (f16)v;
        h4[r] = h;
        l4[r] = (f16)(v - (float)h);
      }
      if (wantRow) {
        const size_t moff = (size_t)mrow * DMODEL + o;
        *(f16x4*)(k_hi + moff) = h4;
        *(f16x4*)(k_lo + moff) = l4;
      }
#pragma unroll
      for (int r = 0; r < 4; r++) {
        T_hi[(size_t)(o + r) * NTOT + mrow] = h4[r];
        T_lo[(size_t)(o + r) * NTOT + mrow] = l4[r];
      }
    }
  }
}

// ---------------------------------------------------------------------------
// logits via MFMA on nh: logits[b,n] = ainv[b]*(dot(nh[n],rq[b])*c1[n]
//                                              + rqsum[b]*c2[n])
// ---------------------------------------------------------------------------
__global__ __launch_bounds__(256)
void logits_mfma(const f16* __restrict__ nh_hi, const f16* __restrict__ nh_lo,
                 const f16* __restrict__ rq_hi, const f16* __restrict__ rq_lo,
                 const float* __restrict__ c1, const float* __restrict__ c2,
                 const float* __restrict__ ainv, const float* __restrict__ rqsum,
                 float* __restrict__ out) {
  __shared__ __align__(16) f16 As[128][64];  // nh tile (A operand, free=n)
  __shared__ __align__(16) f16 Bs[128][64];  // rq (B operand, free=batch)
  const int t = threadIdx.x;
  const int n0 = blockIdx.x * 128;
  const int w = t >> 6, lane = t & 63;
  const int l15 = lane & 15, lq = lane >> 4;
  const int wm = w >> 1, wn = w & 1;  // wm: batch half, wn: n half
  const int sc = (lane & 7) ^ (lane >> 3);
  const int srow = lane >> 3;

  f32x4 acc[4][4];  // [fo(n)][fm(batch)]
#pragma unroll
  for (int a = 0; a < 4; a++)
#pragma unroll
    for (int b = 0; b < 4; b++)
#pragma unroll
      for (int r = 0; r < 4; r++) acc[a][b][r] = 0.f;

  for (int k0 = 0; k0 < DMODEL; k0 += 32) {
    __syncthreads();
#pragma unroll
    for (int i = 0; i < 4; i++) {
      const int rb = (w * 4 + i) * 8;
      const f16* asrc = ((sc < 4) ? nh_hi : nh_lo) +
          (size_t)(n0 + rb + srow) * DMODEL + k0 + (sc & 3) * 8;
      __builtin_amdgcn_global_load_lds(
          (__attribute__((address_space(1))) void*)asrc,
          (__attribute__((address_space(3))) void*)&As[rb][0], 16, 0, 0);
      const f16* bsrc = ((sc < 4) ? rq_hi : rq_lo) +
          (size_t)(rb + srow) * DMODEL + k0 + (sc & 3) * 8;
      __builtin_amdgcn_global_load_lds(
          (__attribute__((address_space(1))) void*)bsrc,
          (__attribute__((address_space(3))) void*)&Bs[rb][0], 16, 0, 0);
    }
    __syncthreads();

    f16x8 ah[4], al[4];  // nh (A operand), free = n
#pragma unroll
    for (int fo = 0; fo < 4; fo++) {
      const int row = wn * 64 + fo * 16 + l15;
      const int e = row & 7;
      ah[fo] = *(const f16x8*)&As[row][(lq ^ e) * 8];
      al[fo] = *(const f16x8*)&As[row][((lq + 4) ^ e) * 8];
    }
    f16x8 bh[4], bl[4];  // rq (B operand), free = batch
#pragma unroll
    for (int fm = 0; fm < 4; fm++) {
      const int row = wm * 64 + fm * 16 + l15;
      const int e = row & 7;
      bh[fm] = *(const f16x8*)&Bs[row][(lq ^ e) * 8];
      bl[fm] = *(const f16x8*)&Bs[row][((lq + 4) ^ e) * 8];
    }
#pragma unroll
    for (int fo = 0; fo < 4; fo++)
#pragma unroll
      for (int fm = 0; fm < 4; fm++) {
        f32x4 a = acc[fo][fm];
        a = __builtin_amdgcn_mfma_f32_16x16x32_f16(ah[fo], bh[fm], a, 0, 0, 0);
        a = __builtin_amdgcn_mfma_f32_16x16x32_f16(ah[fo], bl[fm], a, 0, 0, 0);
        a = __builtin_amdgcn_mfma_f32_16x16x32_f16(al[fo], bh[fm], a, 0, 0, 0);
        acc[fo][fm] = a;
      }
  }
#pragma unroll
  for (int fm = 0; fm < 4; fm++) {
    const int b = wm * 64 + fm * 16 + l15;
    const float am = ainv[b];
    const float rs = rqsum[b];
#pragma unroll
    for (int fo = 0; fo < 4; fo++) {
      const int nb = n0 + wn * 64 + fo * 16 + lq * 4;
      const float4 c1v = *(const float4*)(c1 + nb);
      const float4 c2v = *(const float4*)(c2 + nb);
      const float c1a[4] = {c1v.x, c1v.y, c1v.z, c1v.w};
      const float c2a[4] = {c2v.x, c2v.y, c2v.z, c2v.w};
      float4 o4;
      float ov[4];
#pragma unroll
      for (int r = 0; r < 4; r++)
        ov[r] = am * (acc[fo][fm][r] * c1a[r] + rs * c2a[r]);
      o4.x = ov[0]; o4.y = ov[1]; o4.z = ov[2]; o4.w = ov[3];
      *(float4*)(out + (size_t)b * NTOT + nb) = o4;
    }
  }
}

// ---------------------------------------------------------------------------
// LN-fused GEMM, fp32 output (for q projection).
// ---------------------------------------------------------------------------
__global__ __launch_bounds__(256)
void ln_gemm_f32(const float* __restrict__ A, const float* __restrict__ mean,
                 const float* __restrict__ rstd, const float* __restrict__ g,
                 const float* __restrict__ bln, const float* __restrict__ W,
                 const float* __restrict__ bias, float* __restrict__ out) {
  __shared__ float As[16][68];
  __shared__ float Ws[16][68];
  const int t = threadIdx.x;
  const int m0 = blockIdx.y << 6, n0 = blockIdx.x << 6;
  const int tm = t >> 4, tn = t & 15;
  const int lr = t >> 2;
  const int lk = (t & 3) << 2;
  const float muL = mean[m0 + lr];
  const float rsL = rstd[m0 + lr];
  float acc[4][4] = {};
  for (int k0 = 0; k0 < DMODEL; k0 += 16) {
    float4 a4 = *(const float4*)(A + (size_t)(m0 + lr) * DMODEL + k0 + lk);
    float4 g4 = *(const float4*)(g + k0 + lk);
    float4 b4 = *(const float4*)(bln + k0 + lk);
    As[lk + 0][lr] = (a4.x - muL) * rsL * g4.x + b4.x;
    As[lk + 1][lr] = (a4.y - muL) * rsL * g4.y + b4.y;
    As[lk + 2][lr] = (a4.z - muL) * rsL * g4.z + b4.z;
    As[lk + 3][lr] = (a4.w - muL) * rsL * g4.w + b4.w;
    float4 w4 = *(const float4*)(W + (size_t)(n0 + lr) * DMODEL + k0 + lk);
    Ws[lk + 0][lr] = w4.x;
    Ws[lk + 1][lr] = w4.y;
    Ws[lk + 2][lr] = w4.z;
    Ws[lk + 3][lr] = w4.w;
    __syncthreads();
#pragma unroll
    for (int kk = 0; kk < 16; kk++) {
      const float4 av = *(const float4*)(&As[kk][tm * 4]);
      const float4 bv = *(const float4*)(&Ws[kk][tn * 4]);
      const float a[4] = {av.x, av.y, av.z, av.w};
      const float b[4] = {bv.x, bv.y, bv.z, bv.w};
#pragma unroll
      for (int i = 0; i < 4; i++)
#pragma unroll
        for (int j = 0; j < 4; j++) acc[i][j] += a[i] * b[j];
    }
    __syncthreads();
  }
  const float4 bia = *(const float4*)(bias + n0 + tn * 4);
  const float bb[4] = {bia.x, bia.y, bia.z, bia.w};
#pragma unroll
  for (int i = 0; i < 4; i++) {
    const int m = m0 + tm * 4 + i;
    float4 o4;
    o4.x = acc[i][0] + bb[0];
    o4.y = acc[i][1] + bb[1];
    o4.z = acc[i][2] + bb[2];
    o4.w = acc[i][3] + bb[3];
    *(float4*)(out + (size_t)m * DMODEL + n0 + tn * 4) = o4;
  }
}

// ---------------------------------------------------------------------------
// Plain small GEMM: out = act(A @ W^T + bias [+ add])
// ---------------------------------------------------------------------------
__global__ __launch_bounds__(256)
void gemm_bias(const float* __restrict__ A, const float* __restrict__ W,
               const float* __restrict__ bias, const float* __restrict__ add,
               float* __restrict__ out, int relu) {
  __shared__ float As[16][68];
  __shared__ float Ws[16][68];
  const int t = threadIdx.x;
  const int m0 = blockIdx.y << 6, n0 = blockIdx.x << 6;
  const int tm = t >> 4, tn = t & 15;
  const int lr = t >> 2;
  const int lk = (t & 3) << 2;
  float acc[4][4] = {};
  for (int k0 = 0; k0 < DMODEL; k0 += 16) {
    float4 a4 = *(const float4*)(A + (size_t)(m0 + lr) * DMODEL + k0 + lk);
    As[lk + 0][lr] = a4.x;
    As[lk + 1][lr] = a4.y;
    As[lk + 2][lr] = a4.z;
    As[lk + 3][lr] = a4.w;
    float4 w4 = *(const float4*)(W + (size_t)(n0 + lr) * DMODEL + k0 + lk);
    Ws[lk + 0][lr] = w4.x;
    Ws[lk + 1][lr] = w4.y;
    Ws[lk + 2][lr] = w4.z;
    Ws[lk + 3][lr] = w4.w;
    __syncthreads();
#pragma unroll
    for (int kk = 0; kk < 16; kk++) {
      const float4 av = *(const float4*)(&As[kk][tm * 4]);
      const float4 bv = *(const float4*)(&Ws[kk][tn * 4]);
      const float a[4] = {av.x, av.y, av.z, av.w};
      const float b[4] = {bv.x, bv.y, bv.z, bv.w};
#pragma unroll
      for (int i = 0; i < 4; i++)
#pragma unroll
        for (int j = 0; j < 4; j++) acc[i][j] += a[i] * b[j];
    }
    __syncthreads();
  }
  const float4 bia = *(const float4*)(bias + n0 + tn * 4);
  const float bb[4] = {bia.x, bia.y, bia.z, bia.w};
#pragma unroll
  for (int i = 0; i < 4; i++) {
    const int m = m0 + tm * 4 + i;
    float v[4];
#pragma unroll
    for (int j = 0; j < 4; j++) v[j] = acc[i][j] + bb[j];
    if (add) {
      const float4 a4 = *(const float4*)(add + (size_t)m * DMODEL + n0 + tn * 4);
      v[0] += a4.x; v[1] += a4.y; v[2] += a4.z; v[3] += a4.w;
    }
    if (relu) {
#pragma unroll
      for (int j = 0; j < 4; j++) v[j] = fmaxf(v[j], 0.f);
    }
    float4 o4 = {v[0], v[1], v[2], v[3]};
    *(float4*)(out + (size_t)m * DMODEL + n0 + tn * 4) = o4;
  }
}

// ---------------------------------------------------------------------------
// Split xi (fp32) into beta-scaled fp16 hi/lo pair.
// ---------------------------------------------------------------------------
__global__ __launch_bounds__(256)
void split_xi_k(const float* __restrict__ xi, f16* __restrict__ hi,
                f16* __restrict__ lo) {
  const int i = blockIdx.x * 256 + threadIdx.x;  // over float4s: 24576 total
  float4 v = ((const float4*)xi)[i];
  float s[4] = {v.x * BETA, v.y * BETA, v.z * BETA, v.w * BETA};
  f16x4 h4, l4;
#pragma unroll
  for (int j = 0; j < 4; j++) {
    f16 h = (f16)s[j];
    h4[j] = h;
    l4[j] = (f16)(s[j] - (float)h);
  }
  ((f16x4*)hi)[i] = h4;
  ((f16x4*)lo)[i] = l4;
}

// ---------------------------------------------------------------------------
// MFMA flash attention round, full hi/lo precision (fp32-accurate).
// v4: double-buffered global_load_lds staging, ONE barrier per iter.
// LDS per tile: krow [2][32][48] linear (chunks 0..383) + ptT [2][48][32]
// with chunk-XOR swizzle pc = nc ^ (d&3) (chunks 384..767). Swizzle is
// inverse-applied on the GLOBAL source (rule #21), LDS dest stays linear.
// Operand values bitwise-identical to v3.
// ---------------------------------------------------------------------------
#define FCHUNK 64
#define FROWS (NTOT / FCHUNK)  // 512

__global__ __launch_bounds__(256)
void flash_round(const f16* __restrict__ k_hi, const f16* __restrict__ k_lo,
                 const f16* __restrict__ pvT_hi, const f16* __restrict__ pvT_lo,
                 const f16* __restrict__ xi_hi, const f16* __restrict__ xi_lo,
                 float* __restrict__ part_ml, float* __restrict__ part_o) {
  const int h = blockIdx.y, chunk = blockIdx.x;
  const int tid = threadIdx.x, w = tid >> 6, lane = tid & 63;
  const int l15 = lane & 15, lq = lane >> 4;
  const int b0 = w * 32;

  // stage[buf]: f16 offsets 0..3071 = krow [tsel][32 n][48 d];
  //             3072..6143 = ptT [tsel][48 d][32 n] (chunk-swizzled)
  __shared__ __align__(16) f16 stage[2][6144];
  __shared__ __align__(16) f16 pHi[4][32][40];
  __shared__ __align__(16) f16 pLo[4][32][40];

  const int nbase = chunk * FROWS;

  // 12 issue slots (3 per wave); slot s covers 16B-chunks [s*64, s*64+64)
  const f16* gsrc[3];
  int gstep[3];
#pragma unroll
  for (int g = 0; g < 3; g++) {
    const int s = w * 3 + g;
    const int ci = s * 64 + lane;
    if (s < 6) {  // krow: chunk = tsel*192 + r*6 + dc
      const int tsel = ci / 192, rem = ci % 192;
      const int r = rem / 6, dc = rem % 6;
      gsrc[g] = (tsel ? k_lo : k_hi) + (size_t)(nbase + r) * DMODEL + h * DH + dc * 8;
      gstep[g] = 32 * DMODEL;
    } else {      // ptT: chunk = 384 + tsel*192 + d*4 + pc; logical nc = pc^(d&3)
      const int j = ci - 384;
      const int tsel = j / 192, rem = j % 192;
      const int d = rem / 4, pc = rem % 4;
      const int nc = pc ^ (d & 3);
      gsrc[g] = (tsel ? pvT_lo : pvT_hi) + (size_t)(h * DH + d) * NTOT + nbase + nc * 8;
      gstep[g] = 32;
    }
  }

  const f16x8 zf = {};
  f16x8 xqh[2][2], xql[2][2];
#pragma unroll
  for (int bt = 0; bt < 2; bt++) {
    const size_t xoff = (size_t)(b0 + bt * 16 + l15) * DMODEL + h * DH;
    xqh[bt][0] = *(const f16x8*)(xi_hi + xoff + lq * 8);
    xql[bt][0] = *(const f16x8*)(xi_lo + xoff + lq * 8);
    const size_t xo1 = xoff + 32 + (lq & 1) * 8;
    f16x8 th = *(const f16x8*)(xi_hi + xo1);
    f16x8 tl = *(const f16x8*)(xi_lo + xo1);
    xqh[bt][1] = (lq < 2) ? th : zf;
    xql[bt][1] = (lq < 2) ? tl : zf;
  }

  float m[2] = {-1e30f, -1e30f}, lsum[2] = {0.f, 0.f};
  f32x4 O[3][2];
#pragma unroll
  for (int mt = 0; mt < 3; mt++)
#pragma unroll
    for (int bt = 0; bt < 2; bt++)
#pragma unroll
      for (int j = 0; j < 4; j++) O[mt][bt][j] = 0.f;

  // prologue: DMA tile 0 into buf 0
#pragma unroll
  for (int g = 0; g < 3; g++) {
    __builtin_amdgcn_global_load_lds(
        (__attribute__((address_space(1))) void*)gsrc[g],
        (__attribute__((address_space(3))) void*)&stage[0][(w * 3 + g) * 512],
        16, 0, 0);
    gsrc[g] += gstep[g];
  }
  __syncthreads();  // drains vmcnt(0): tile 0 resident

  int cur = 0;
  for (int it = 0; it < 16; it++) {
    // issue next tile's DMA into the other buffer (read next iter)
    if (it < 15) {
#pragma unroll
      for (int g = 0; g < 3; g++) {
        __builtin_amdgcn_global_load_lds(
            (__attribute__((address_space(1))) void*)gsrc[g],
            (__attribute__((address_space(3))) void*)&stage[cur ^ 1][(w * 3 + g) * 512],
            16, 0, 0);
        gsrc[g] += gstep[g];
      }
    }
    const f16* st = stage[cur];

    f16x8 akh[2][2], akl[2][2];
#pragma unroll
    for (int nt = 0; nt < 2; nt++) {
      const int row = nt * 16 + l15;
      akh[nt][0] = *(const f16x8*)&st[row * 48 + lq * 8];
      akl[nt][0] = *(const f16x8*)&st[1536 + row * 48 + lq * 8];
      f16x8 t0 = *(const f16x8*)&st[row * 48 + 32 + (lq & 1) * 8];
      f16x8 t1 = *(const f16x8*)&st[1536 + row * 48 + 32 + (lq & 1) * 8];
      akh[nt][1] = (lq < 2) ? t0 : zf;
      akl[nt][1] = (lq < 2) ? t1 : zf;
    }
    f32x4 S[2][2];
#pragma unroll
    for (int nt = 0; nt < 2; nt++)
#pragma unroll
      for (int bt = 0; bt < 2; bt++) {
        f32x4 s = {};
        s = __builtin_amdgcn_mfma_f32_16x16x32_f16(akh[nt][0], xqh[bt][0], s, 0, 0, 0);
        s = __builtin_amdgcn_mfma_f32_16x16x32_f16(akh[nt][1], xqh[bt][1], s, 0, 0, 0);
        s = __builtin_amdgcn_mfma_f32_16x16x32_f16(akh[nt][0], xql[bt][0], s, 0, 0, 0);
        s = __builtin_amdgcn_mfma_f32_16x16x32_f16(akh[nt][1], xql[bt][1], s, 0, 0, 0);
        s = __builtin_amdgcn_mfma_f32_16x16x32_f16(akl[nt][0], xqh[bt][0], s, 0, 0, 0);
        s = __builtin_amdgcn_mfma_f32_16x16x32_f16(akl[nt][1], xqh[bt][1], s, 0, 0, 0);
        S[nt][bt] = s;
      }
    float sc[2];
#pragma unroll
    for (int bt = 0; bt < 2; bt++) {
      float mx = S[0][bt][0];
#pragma unroll
      for (int r = 1; r < 4; r++) mx = fmaxf(mx, S[0][bt][r]);
#pragma unroll
      for (int r = 0; r < 4; r++) mx = fmaxf(mx, S[1][bt][r]);
      mx = fmaxf(mx, __shfl_xor(mx, 16));
      mx = fmaxf(mx, __shfl_xor(mx, 32));
      const float mnew = fmaxf(m[bt], mx);
      sc[bt] = __expf(m[bt] - mnew);
      float ps = 0.f;
#pragma unroll
      for (int nt = 0; nt < 2; nt++) {
        f16x4 ph, pl;
#pragma unroll
        for (int r = 0; r < 4; r++) {
          const float p = __expf(S[nt][bt][r] - mnew);
          ps += p;
          const f16 hh = (f16)p;
          ph[r] = hh;
          pl[r] = (f16)(p - (float)hh);
        }
        *(f16x4*)&pHi[w][bt * 16 + l15][nt * 16 + lq * 4] = ph;
        *(f16x4*)&pLo[w][bt * 16 + l15][nt * 16 + lq * 4] = pl;
      }
      ps += __shfl_xor(ps, 16);
      ps += __shfl_xor(ps, 32);
      lsum[bt] = lsum[bt] * sc[bt] + ps;
      m[bt] = mnew;
    }
    __asm__ volatile("s_waitcnt lgkmcnt(0)" ::: "memory");
    f16x8 avh[3], avl[3];
#pragma unroll
    for (int mt = 0; mt < 3; mt++) {
      const int d = mt * 16 + l15;
      const int po = (lq ^ (d & 3)) * 8;  // swizzled phys chunk
      avh[mt] = *(const f16x8*)&st[3072 + d * 32 + po];
      avl[mt] = *(const f16x8*)&st[3072 + 1536 + d * 32 + po];
    }
    f16x8 pbh[2], pbl[2];
#pragma unroll
    for (int bt = 0; bt < 2; bt++) {
      pbh[bt] = *(const f16x8*)&pHi[w][bt * 16 + l15][lq * 8];
      pbl[bt] = *(const f16x8*)&pLo[w][bt * 16 + l15][lq * 8];
    }
#pragma unroll
    for (int mt = 0; mt < 3; mt++)
#pragma unroll
      for (int bt = 0; bt < 2; bt++) {
#pragma unroll
        for (int j = 0; j < 4; j++) O[mt][bt][j] *= sc[bt];
        f32x4 o = O[mt][bt];
        o = __builtin_amdgcn_mfma_f32_16x16x32_f16(avh[mt], pbh[bt], o, 0, 0, 0);
        o = __builtin_amdgcn_mfma_f32_16x16x32_f16(avh[mt], pbl[bt], o, 0, 0, 0);
        o = __builtin_amdgcn_mfma_f32_16x16x32_f16(avl[mt], pbh[bt], o, 0, 0, 0);
        O[mt][bt] = o;
      }

    if (it < 15) {
      __syncthreads();  // vmcnt(0) drain: next tile resident; all reads of cur done
      cur ^= 1;
    }
  }
  const int pc = h * FCHUNK + chunk;
  if (lq == 0) {
#pragma unroll
    for (int bt = 0; bt < 2; bt++) {
      float* pm = part_ml + ((size_t)pc * BSZ + b0 + bt * 16 + l15) * 2;
      pm[0] = m[bt];
      pm[1] = lsum[bt];
    }
  }
#pragma unroll
  for (int mt = 0; mt < 3; mt++)
#pragma unroll
    for (int bt = 0; bt < 2; bt++) {
      float* po = part_o + ((size_t)pc * BSZ + b0 + bt * 16 + l15) * 48 +
                  mt * 16 + lq * 4;
      *(f32x4*)po = O[mt][bt];
    }
}

// ---------------------------------------------------------------------------
// Combine 64 chunk-partials per (b,h). Grid = B*H blocks of 64 threads.
// ---------------------------------------------------------------------------
__global__ __launch_bounds__(64)
void hopfield_combine(const float* __restrict__ part_ml,
                      const float* __restrict__ part_o, float* __restrict__ dst) {
  const int bh = blockIdx.x;  // h*128 + b
  const int h = bh >> 7, b = bh & 127;
  const int c = threadIdx.x;
  __shared__ float w[64];
  const float* pm = part_ml + ((size_t)(h * 64 + c) * BSZ + b) * 2;
  const float mp = pm[0];
  const float lp = pm[1];
  float M = mp;
#pragma unroll
  for (int off = 32; off; off >>= 1) M = fmaxf(M, __shfl_xor(M, off));
  const float wp = __expf(mp - M);
  w[c] = wp;
  float L = lp * wp;
#pragma unroll
  for (int off = 32; off; off >>= 1) L += __shfl_xor(L, off);
  __syncthreads();
  if (c < DH) {
    float o = 0.f;
    for (int p = 0; p < 64; p++)
      o += part_o[((size_t)(h * 64 + p) * BSZ + b) * 48 + c] * w[p];
    dst[(size_t)b * DMODEL + h * DH + c] = o / L;
  }
}

// ---------------------------------------------------------------------------
// Top-4 per row with jax tie-breaking (lower index first).
// ---------------------------------------------------------------------------
__global__ __launch_bounds__(256)
void topk_kernel(const float* __restrict__ logits, float* __restrict__ outIdx) {
  const int b = blockIdx.x;
  const int t = threadIdx.x;
  const float* row = logits + (size_t)b * NTOT;
  float v[4] = {-1e30f, -1e30f, -1e30f, -1e30f};
  int id[4] = {0x7fffffff, 0x7fffffff, 0x7fffffff, 0x7fffffff};
  for (int n = t; n < NTOT; n += 256) {
    const float x = row[n];
    if (x > v[3]) {
      v[3] = x; id[3] = n;
#pragma unroll
      for (int s = 3; s > 0; s--) {
        const bool sw = (v[s] > v[s - 1]) || (v[s] == v[s - 1] && id[s] < id[s - 1]);
        if (sw) {
          float tv = v[s]; v[s] = v[s - 1]; v[s - 1] = tv;
          int ti = id[s]; id[s] = id[s - 1]; id[s - 1] = ti;
        }
      }
    }
  }
  __shared__ float sv[256][4];
  __shared__ int si[256][4];
#pragma unroll
  for (int j = 0; j < 4; j++) { sv[t][j] = v[j]; si[t][j] = id[j]; }
  for (int str = 128; str >= 1; str >>= 1) {
    __syncthreads();
    if (t < str) {
      float a[4], c[4];
      int ai[4], ci[4];
#pragma unroll
      for (int j = 0; j < 4; j++) {
        a[j] = sv[t][j]; ai[j] = si[t][j];
        c[j] = sv[t + str][j]; ci[j] = si[t + str][j];
      }
      float rv[4]; int ri[4];
      int p = 0, q = 0;
#pragma unroll
      for (int oo = 0; oo < 4; oo++) {
        const bool ta = (a[p] > c[q]) || (a[p] == c[q] && ai[p] < ci[q]);
        if (ta) { rv[oo] = a[p]; ri[oo] = ai[p]; p++; }
        else    { rv[oo] = c[q]; ri[oo] = ci[q]; q++; }
      }
#pragma unroll
      for (int j = 0; j < 4; j++) { sv[t][j] = rv[j]; si[t][j] = ri[j]; }
    }
  }
  if (t == 0) {
#pragma unroll
    for (int j = 0; j < 4; j++) outIdx[b * 4 + j] = (float)si[0][j];
  }
}

// ---------------------------------------------------------------------------
extern "C" void kernel_launch(void* const* d_in, const int* in_sizes, int n_in,
                              void* d_out, int out_size, void* d_ws, size_t ws_size,
                              hipStream_t stream) {
  const float* qe    = (const float*)d_in[0];
  const float* mb    = (const float*)d_in[1];
  const float* ln_kg = (const float*)d_in[2];
  const float* ln_kb = (const float*)d_in[3];
  const float* ln_qg = (const float*)d_in[4];
  const float* ln_qb = (const float*)d_in[5];
  const float* ln_vg = (const float*)d_in[6];
  const float* ln_vb = (const float*)d_in[7];
  const float* Wq = (const float*)d_in[8];
  const float* bq = (const float*)d_in[9];
  const float* Wk = (const float*)d_in[10];
  const float* bk = (const float*)d_in[11];
  const float* Wv = (const float*)d_in[12];
  const float* bv = (const float*)d_in[13];
  const float* Wo = (const float*)d_in[14];
  const float* bo = (const float*)d_in[15];
  const float* W1 = (const float*)d_in[16];
  const float* b1 = (const float*)d_in[17];
  const float* W2 = (const float*)d_in[18];
  const float* b2 = (const float*)d_in[19];

  float* out = (float*)d_out;  // [0..511] top indices (as float), then logits
  float* logits = out + BSZ * 4;

  float* ws = (float*)d_ws;
  size_t off = 0;
  auto alloc = [&](size_t n) { float* p = ws + off; off += n; return p; };
  const size_t ND2 = (size_t)NTOT * DMODEL / 2;  // one fp16 N*D buffer, in floats
  float* c1      = alloc(NTOT);
  float* c2      = alloc(NTOT);
  float* q_mean  = alloc(128);
  float* q_rstd  = alloc(128);
  float* rq_inv  = alloc(128);
  float* rq_sum  = alloc(128);
  float* pad_    = alloc(256);
  f16* k_hi  = (f16*)alloc(ND2);  // [N][768] row-major (QK operand)
  f16* k_lo  = (f16*)alloc(ND2);
  f16* T_hi  = (f16*)alloc(ND2);  // [768][N]: K^T for rounds 0-4, then V^T
  f16* T_lo  = (f16*)alloc(ND2);
  f16* nh_hi = (f16*)alloc(ND2);  // normalized mb, fp16 hi/lo
  f16* nh_lo = (f16*)alloc(ND2);
  float* part_ml = alloc((size_t)NHEAD * FCHUNK * BSZ * 2);
  float* part_o  = alloc((size_t)NHEAD * FCHUNK * BSZ * 48);
  float* xi   = alloc((size_t)BSZ * DMODEL);
  float* conv = alloc((size_t)BSZ * DMODEL);
  float* comb = alloc((size_t)BSZ * DMODEL);
  float* h1   = alloc((size_t)BSZ * DMODEL);
  f16* xi_hi = (f16*)alloc((size_t)BSZ * DMODEL / 2);
  f16* xi_lo = (f16*)alloc((size_t)BSZ * DMODEL / 2);
  f16* rq_hi = (f16*)alloc((size_t)BSZ * DMODEL / 2);
  f16* rq_lo = (f16*)alloc((size_t)BSZ * DMODEL / 2);
  f16* Wc_hi = (f16*)alloc((size_t)2 * DMODEL * DMODEL / 2);  // [1536][768]
  f16* Wc_lo = (f16*)alloc((size_t)2 * DMODEL * DMODEL / 2);
  float* biasc = alloc(2 * DMODEL);
  (void)ws_size; (void)in_sizes; (void)n_in; (void)out_size; (void)pad_;

  // 1. stats (q) + fused stats/normalize/split (mb) + W prep
  row_stats<<<BSZ / 4, 256, 0, stream>>>(qe, BSZ, q_mean, q_rstd, nullptr);
  stats_norm_mb<<<NTOT / 4, 256, 0, stream>>>(mb, nh_hi, nh_lo, c1, c2);
  prep_w<<<2 * DMODEL / 4, 256, 0, stream>>>(Wk, bk, ln_kg, ln_kb,
                                             Wv, bv, ln_vg, ln_vb,
                                             Wc_hi, Wc_lo, biasc);

  // 2. K-half projection (k row-major + K^T into T); q (xi) fp32
  proj_mfma<<<dim3(DMODEL / 128, NTOT / 128), 256, 0, stream>>>(
      nh_hi, nh_lo, Wc_hi, Wc_lo, biasc, k_hi, k_lo, T_hi, T_lo, 0);
  ln_gemm_f32<<<dim3(DMODEL / 64, BSZ / 64), 256, 0, stream>>>(
      qe, q_mean, q_rstd, ln_qg, ln_qb, Wq, bq, xi);

  // 3. Hopfield rounds 0-4 (PV source = K^T in T)
  for (int r = 0; r < 5; r++) {
    split_xi_k<<<96, 256, 0, stream>>>(xi, xi_hi, xi_lo);
    flash_round<<<dim3(FCHUNK, NHEAD), 256, 0, stream>>>(
        k_hi, k_lo, T_hi, T_lo, xi_hi, xi_lo, part_ml, part_o);
    hopfield_combine<<<BSZ * NHEAD, 64, 0, stream>>>(part_ml, part_o, xi);
  }

  // 3b. V-half projection: writes V^T over the (now dead) K^T buffer
  proj_mfma<<<dim3(DMODEL / 128, NTOT / 128), 256, 0, stream>>>(
      nh_hi, nh_lo, Wc_hi, Wc_lo, biasc, k_hi, k_lo, T_hi, T_lo, DMODEL);

  // 3c. readout round (PV source = V^T in T)
  split_xi_k<<<96, 256, 0, stream>>>(xi, xi_hi, xi_lo);
  flash_round<<<dim3(FCHUNK, NHEAD), 256, 0, stream>>>(
      k_hi, k_lo, T_hi, T_lo, xi_hi, xi_lo, part_ml, part_o);
  hopfield_combine<<<BSZ * NHEAD, 64, 0, stream>>>(part_ml, part_o, conv);

  // 4. readout MLP
  gemm_bias<<<dim3(DMODEL / 64, BSZ / 64), 256, 0, stream>>>(conv, Wo, bo, qe, comb, 0);
  gemm_bias<<<dim3(DMODEL / 64, BSZ / 64), 256, 0, stream>>>(comb, W1, b1, nullptr, h1, 1);
  float* rq = conv;  // conv dead after comb computed; reuse for rq
  gemm_bias<<<dim3(DMODEL / 64, BSZ / 64), 256, 0, stream>>>(h1, W2, b2, nullptr, rq, 0);

  // 5. cosine logits: split rq, then MFMA over nh with LN-reconstruction fold
  rq_prep<<<BSZ / 4, 256, 0, stream>>>(rq, rq_hi, rq_lo, rq_inv, rq_sum);
  logits_mfma<<<NTOT / 128, 256, 0, stream>>>(nh_hi, nh_lo, rq_hi, rq_lo,
                                              c1, c2, rq_inv, rq_sum, logits);

  // 6. top-4 indices
  topk_kernel<<<BSZ, 256, 0, stream>>>(logits, out);
}

// Round 6
// 1353.304 us; speedup vs baseline: 1.0177x; 1.0177x over previous
//
#include <hip/hip_runtime.h>
#include <math.h>

#define NTOT 32768
#define DMODEL 768
#define BSZ 128
#define NHEAD 16
#define DH 48
#define BETA 0.25f

typedef _Float16 f16;
typedef f16 f16x8 __attribute__((ext_vector_type(8)));
typedef f16 f16x4 __attribute__((ext_vector_type(4)));
typedef float f32x4 __attribute__((ext_vector_type(4)));

// ---------------------------------------------------------------------------
// Row stats: mean, rstd (LN, biased var, eps=1e-5), optional l2inv of raw row.
// ---------------------------------------------------------------------------
__global__ __launch_bounds__(256)
void row_stats(const float* __restrict__ X, int M, float* __restrict__ mean,
               float* __restrict__ rstd, float* __restrict__ l2inv) {
  const int row = blockIdx.x * 4 + (threadIdx.x >> 6);
  const int lane = threadIdx.x & 63;
  if (row >= M) return;
  const float* x = X + (size_t)row * DMODEL;
  float s = 0.f, s2 = 0.f;
  for (int i = lane; i < DMODEL; i += 64) {
    float v = x[i];
    s += v; s2 += v * v;
  }
#pragma unroll
  for (int off = 32; off; off >>= 1) {
    s  += __shfl_xor(s, off);
    s2 += __shfl_xor(s2, off);
  }
  if (lane == 0) {
    float mu = s * (1.f / DMODEL);
    float var = s2 * (1.f / DMODEL) - mu * mu;
    mean[row] = mu;
    rstd[row] = rsqrtf(var + 1e-5f);
    if (l2inv) l2inv[row] = 1.f / fmaxf(sqrtf(s2), 1e-12f);
  }
}

// ---------------------------------------------------------------------------
// Fused: stats over mb row + nh = (mb-mu)*rstd f16 hi/lo + logits fold consts.
// ---------------------------------------------------------------------------
__global__ __launch_bounds__(256)
void stats_norm_mb(const float* __restrict__ mb, f16* __restrict__ nh_hi,
                   f16* __restrict__ nh_lo, float* __restrict__ c1,
                   float* __restrict__ c2) {
  const int row = blockIdx.x * 4 + (threadIdx.x >> 6);
  const int lane = threadIdx.x & 63;
  const float* x = mb + (size_t)row * DMODEL;
  float v[12];
  float s = 0.f, s2 = 0.f;
#pragma unroll
  for (int j = 0; j < 3; j++) {
    const float4 v4 = *(const float4*)(x + lane * 4 + j * 256);
    v[j * 4 + 0] = v4.x; v[j * 4 + 1] = v4.y;
    v[j * 4 + 2] = v4.z; v[j * 4 + 3] = v4.w;
    s += v4.x + v4.y + v4.z + v4.w;
    s2 += v4.x * v4.x + v4.y * v4.y + v4.z * v4.z + v4.w * v4.w;
  }
#pragma unroll
  for (int off = 32; off; off >>= 1) {
    s  += __shfl_xor(s, off);
    s2 += __shfl_xor(s2, off);
  }
  const float mu = s * (1.f / DMODEL);
  const float var = s2 * (1.f / DMODEL) - mu * mu;
  const float istd = sqrtf(var + 1e-5f);
  const float rs = 1.f / istd;
  f16* oh = nh_hi + (size_t)row * DMODEL;
  f16* ol = nh_lo + (size_t)row * DMODEL;
#pragma unroll
  for (int j = 0; j < 3; j++) {
    f16x4 h4, l4;
#pragma unroll
    for (int q = 0; q < 4; q++) {
      const float sv = (v[j * 4 + q] - mu) * rs;
      const f16 h = (f16)sv;
      h4[q] = h;
      l4[q] = (f16)(sv - (float)h);
    }
    *(f16x4*)(oh + lane * 4 + j * 256) = h4;
    *(f16x4*)(ol + lane * 4 + j * 256) = l4;
  }
  if (lane == 0) {
    const float l2i = 1.f / fmaxf(sqrtf(s2), 1e-12f);
    c1[row] = 20.f * l2i * istd;
    c2[row] = 20.f * l2i * mu;
  }
}

// ---------------------------------------------------------------------------
// rq_prep: per-row sum, l2inv, and f16 hi/lo split of rq (128 rows).
// ---------------------------------------------------------------------------
__global__ __launch_bounds__(256)
void rq_prep(const float* __restrict__ rq, f16* __restrict__ hi,
             f16* __restrict__ lo, float* __restrict__ ainv,
             float* __restrict__ rqsum) {
  const int row = blockIdx.x * 4 + (threadIdx.x >> 6);
  const int lane = threadIdx.x & 63;
  const float* x = rq + (size_t)row * DMODEL;
  f16* oh = hi + (size_t)row * DMODEL;
  f16* ol = lo + (size_t)row * DMODEL;
  float s = 0.f, s2 = 0.f;
#pragma unroll
  for (int j = 0; j < 3; j++) {
    const int d = lane * 4 + j * 256;
    const float4 v4 = *(const float4*)(x + d);
    const float vv[4] = {v4.x, v4.y, v4.z, v4.w};
    f16x4 h4, l4;
#pragma unroll
    for (int q = 0; q < 4; q++) {
      s += vv[q]; s2 += vv[q] * vv[q];
      const f16 h = (f16)vv[q];
      h4[q] = h;
      l4[q] = (f16)(vv[q] - (float)h);
    }
    *(f16x4*)(oh + d) = h4;
    *(f16x4*)(ol + d) = l4;
  }
#pragma unroll
  for (int off = 32; off; off >>= 1) {
    s  += __shfl_xor(s, off);
    s2 += __shfl_xor(s2, off);
  }
  if (lane == 0) {
    rqsum[row] = s;
    ainv[row] = 1.f / fmaxf(sqrtf(s2), 1e-12f);
  }
}

// ---------------------------------------------------------------------------
// prep_w: combined W' (o<768: g_k*Wk rows; o>=768: g_v*Wv rows), scaled x16,
// split fp16 hi/lo; biasc[o] = bias[o] + sum_d bln[d]*W[o,d].
// ---------------------------------------------------------------------------
__global__ __launch_bounds__(256)
void prep_w(const float* __restrict__ Wk, const float* __restrict__ bk,
            const float* __restrict__ gk, const float* __restrict__ blnk,
            const float* __restrict__ Wv, const float* __restrict__ bv,
            const float* __restrict__ gv, const float* __restrict__ blnv,
            f16* __restrict__ Wc_hi, f16* __restrict__ Wc_lo,
            float* __restrict__ biasc) {
  const int o = blockIdx.x * 4 + (threadIdx.x >> 6);  // 0..1535
  const int lane = threadIdx.x & 63;
  const bool isK = o < DMODEL;
  const float* W = isK ? (Wk + (size_t)o * DMODEL)
                       : (Wv + (size_t)(o - DMODEL) * DMODEL);
  const float* g   = isK ? gk : gv;
  const float* bln = isK ? blnk : blnv;
  float bacc = 0.f;
  for (int d = lane * 4; d < DMODEL; d += 256) {
    const float4 wv = *(const float4*)(W + d);
    const float4 g4 = *(const float4*)(g + d);
    const float4 b4 = *(const float4*)(bln + d);
    bacc += wv.x * b4.x + wv.y * b4.y + wv.z * b4.z + wv.w * b4.w;
    const float sv[4] = {wv.x * g4.x * 16.f, wv.y * g4.y * 16.f,
                         wv.z * g4.z * 16.f, wv.w * g4.w * 16.f};
    f16x4 h4, l4;
#pragma unroll
    for (int j = 0; j < 4; j++) {
      const f16 h = (f16)sv[j];
      h4[j] = h;
      l4[j] = (f16)(sv[j] - (float)h);
    }
    *(f16x4*)(Wc_hi + (size_t)o * DMODEL + d) = h4;
    *(f16x4*)(Wc_lo + (size_t)o * DMODEL + d) = l4;
  }
#pragma unroll
  for (int off = 32; off; off >>= 1) bacc += __shfl_xor(bacc, off);
  if (lane == 0) biasc[o] = (isK ? bk[o] : bv[o - DMODEL]) + bacc;
}

// ---------------------------------------------------------------------------
// Half-projection GEMM via 16x16x32 f16 MFMA, 3-term hi/lo split.
// (XCD swizzle removed — R5 A/B: FETCH -75% but dur +10%; not fetch-bound.)
// ---------------------------------------------------------------------------
__global__ __launch_bounds__(256)
void proj_mfma(const f16* __restrict__ nh_hi, const f16* __restrict__ nh_lo,
               const f16* __restrict__ Wc_hi, const f16* __restrict__ Wc_lo,
               const float* __restrict__ biasc,
               f16* __restrict__ k_hi, f16* __restrict__ k_lo,
               f16* __restrict__ T_hi, f16* __restrict__ T_lo, int oc0) {
  __shared__ __align__(16) f16 As[128][64];  // [m][hi/lo-interleaved k]
  __shared__ __align__(16) f16 Bs[128][64];  // [o][...]
  const int t = threadIdx.x;
  const int n0 = oc0 + blockIdx.x * 128;  // global combined o base
  const int m0 = blockIdx.y * 128;
  const int w = t >> 6, lane = t & 63;
  const int l15 = lane & 15, lq = lane >> 4;
  const int wm = w >> 1, wn = w & 1;
  const int sc = (lane & 7) ^ (lane >> 3);
  const int srow = lane >> 3;

  f32x4 acc[4][4];  // [fo][fm]
#pragma unroll
  for (int a = 0; a < 4; a++)
#pragma unroll
    for (int b = 0; b < 4; b++)
#pragma unroll
      for (int r = 0; r < 4; r++) acc[a][b][r] = 0.f;

  for (int k0 = 0; k0 < DMODEL; k0 += 32) {
    __syncthreads();
#pragma unroll
    for (int i = 0; i < 4; i++) {
      const int rb = (w * 4 + i) * 8;
      const f16* asrc = ((sc < 4) ? nh_hi : nh_lo) +
          (size_t)(m0 + rb + srow) * DMODEL + k0 + (sc & 3) * 8;
      __builtin_amdgcn_global_load_lds(
          (__attribute__((address_space(1))) void*)asrc,
          (__attribute__((address_space(3))) void*)&As[rb][0], 16, 0, 0);
      const f16* bsrc = ((sc < 4) ? Wc_hi : Wc_lo) +
          (size_t)(n0 + rb + srow) * DMODEL + k0 + (sc & 3) * 8;
      __builtin_amdgcn_global_load_lds(
          (__attribute__((address_space(1))) void*)bsrc,
          (__attribute__((address_space(3))) void*)&Bs[rb][0], 16, 0, 0);
    }
    __syncthreads();

    f16x8 nhh[4], nhl[4];  // nh (B operand), free = m
#pragma unroll
    for (int fm = 0; fm < 4; fm++) {
      const int row = wm * 64 + fm * 16 + l15;
      const int e = row & 7;
      nhh[fm] = *(const f16x8*)&As[row][(lq ^ e) * 8];
      nhl[fm] = *(const f16x8*)&As[row][((lq + 4) ^ e) * 8];
    }
    f16x8 wh[4], wl[4];  // W' (A operand), free = o
#pragma unroll
    for (int fo = 0; fo < 4; fo++) {
      const int row = wn * 64 + fo * 16 + l15;
      const int e = row & 7;
      wh[fo] = *(const f16x8*)&Bs[row][(lq ^ e) * 8];
      wl[fo] = *(const f16x8*)&Bs[row][((lq + 4) ^ e) * 8];
    }
#pragma unroll
    for (int fo = 0; fo < 4; fo++)
#pragma unroll
      for (int fm = 0; fm < 4; fm++) {
        f32x4 a = acc[fo][fm];
        a = __builtin_amdgcn_mfma_f32_16x16x32_f16(wh[fo], nhh[fm], a, 0, 0, 0);
        a = __builtin_amdgcn_mfma_f32_16x16x32_f16(wh[fo], nhl[fm], a, 0, 0, 0);
        a = __builtin_amdgcn_mfma_f32_16x16x32_f16(wl[fo], nhh[fm], a, 0, 0, 0);
        acc[fo][fm] = a;
      }
  }
  // --- epilogue: /16, +bias, split hi/lo; transposed always, row-major if K ---
  const int oc = n0 + wn * 64;           // global combined o
  const int obase = (oc - oc0) + lq * 4; // local o (0..767)
  const bool wantRow = (oc0 == 0);
#pragma unroll
  for (int fo = 0; fo < 4; fo++) {
    const float4 bb = *(const float4*)(biasc + oc + fo * 16 + lq * 4);
    const float bbv[4] = {bb.x, bb.y, bb.z, bb.w};
    const int o = obase + fo * 16;
#pragma unroll
    for (int fm = 0; fm < 4; fm++) {
      const int mrow = m0 + wm * 64 + fm * 16 + l15;
      f16x4 h4, l4;
#pragma unroll
      for (int r = 0; r < 4; r++) {
        const float v = acc[fo][fm][r] * 0.0625f + bbv[r];
        const f16 h = (f16)v;
        h4[r] = h;
        l4[r] = (f16)(v - (float)h);
      }
      if (wantRow) {
        const size_t moff = (size_t)mrow * DMODEL + o;
        *(f16x4*)(k_hi + moff) = h4;
        *(f16x4*)(k_lo + moff) = l4;
      }
#pragma unroll
      for (int r = 0; r < 4; r++) {
        T_hi[(size_t)(o + r) * NTOT + mrow] = h4[r];
        T_lo[(size_t)(o + r) * NTOT + mrow] = l4[r];
      }
    }
  }
}

// ---------------------------------------------------------------------------
// logits via MFMA on nh: logits[b,n] = ainv[b]*(dot(nh[n],rq[b])*c1[n]
//                                              + rqsum[b]*c2[n])
// ---------------------------------------------------------------------------
__global__ __launch_bounds__(256)
void logits_mfma(const f16* __restrict__ nh_hi, const f16* __restrict__ nh_lo,
                 const f16* __restrict__ rq_hi, const f16* __restrict__ rq_lo,
                 const float* __restrict__ c1, const float* __restrict__ c2,
                 const float* __restrict__ ainv, const float* __restrict__ rqsum,
                 float* __restrict__ out) {
  __shared__ __align__(16) f16 As[128][64];  // nh tile (A operand, free=n)
  __shared__ __align__(16) f16 Bs[128][64];  // rq (B operand, free=batch)
  const int t = threadIdx.x;
  const int n0 = blockIdx.x * 128;
  const int w = t >> 6, lane = t & 63;
  const int l15 = lane & 15, lq = lane >> 4;
  const int wm = w >> 1, wn = w & 1;  // wm: batch half, wn: n half
  const int sc = (lane & 7) ^ (lane >> 3);
  const int srow = lane >> 3;

  f32x4 acc[4][4];  // [fo(n)][fm(batch)]
#pragma unroll
  for (int a = 0; a < 4; a++)
#pragma unroll
    for (int b = 0; b < 4; b++)
#pragma unroll
      for (int r = 0; r < 4; r++) acc[a][b][r] = 0.f;

  for (int k0 = 0; k0 < DMODEL; k0 += 32) {
    __syncthreads();
#pragma unroll
    for (int i = 0; i < 4; i++) {
      const int rb = (w * 4 + i) * 8;
      const f16* asrc = ((sc < 4) ? nh_hi : nh_lo) +
          (size_t)(n0 + rb + srow) * DMODEL + k0 + (sc & 3) * 8;
      __builtin_amdgcn_global_load_lds(
          (__attribute__((address_space(1))) void*)asrc,
          (__attribute__((address_space(3))) void*)&As[rb][0], 16, 0, 0);
      const f16* bsrc = ((sc < 4) ? rq_hi : rq_lo) +
          (size_t)(rb + srow) * DMODEL + k0 + (sc & 3) * 8;
      __builtin_amdgcn_global_load_lds(
          (__attribute__((address_space(1))) void*)bsrc,
          (__attribute__((address_space(3))) void*)&Bs[rb][0], 16, 0, 0);
    }
    __syncthreads();

    f16x8 ah[4], al[4];  // nh (A operand), free = n
#pragma unroll
    for (int fo = 0; fo < 4; fo++) {
      const int row = wn * 64 + fo * 16 + l15;
      const int e = row & 7;
      ah[fo] = *(const f16x8*)&As[row][(lq ^ e) * 8];
      al[fo] = *(const f16x8*)&As[row][((lq + 4) ^ e) * 8];
    }
    f16x8 bh[4], bl[4];  // rq (B operand), free = batch
#pragma unroll
    for (int fm = 0; fm < 4; fm++) {
      const int row = wm * 64 + fm * 16 + l15;
      const int e = row & 7;
      bh[fm] = *(const f16x8*)&Bs[row][(lq ^ e) * 8];
      bl[fm] = *(const f16x8*)&Bs[row][((lq + 4) ^ e) * 8];
    }
#pragma unroll
    for (int fo = 0; fo < 4; fo++)
#pragma unroll
      for (int fm = 0; fm < 4; fm++) {
        f32x4 a = acc[fo][fm];
        a = __builtin_amdgcn_mfma_f32_16x16x32_f16(ah[fo], bh[fm], a, 0, 0, 0);
        a = __builtin_amdgcn_mfma_f32_16x16x32_f16(ah[fo], bl[fm], a, 0, 0, 0);
        a = __builtin_amdgcn_mfma_f32_16x16x32_f16(al[fo], bh[fm], a, 0, 0, 0);
        acc[fo][fm] = a;
      }
  }
#pragma unroll
  for (int fm = 0; fm < 4; fm++) {
    const int b = wm * 64 + fm * 16 + l15;
    const float am = ainv[b];
    const float rs = rqsum[b];
#pragma unroll
    for (int fo = 0; fo < 4; fo++) {
      const int nb = n0 + wn * 64 + fo * 16 + lq * 4;
      const float4 c1v = *(const float4*)(c1 + nb);
      const float4 c2v = *(const float4*)(c2 + nb);
      const float c1a[4] = {c1v.x, c1v.y, c1v.z, c1v.w};
      const float c2a[4] = {c2v.x, c2v.y, c2v.z, c2v.w};
      float4 o4;
      float ov[4];
#pragma unroll
      for (int r = 0; r < 4; r++)
        ov[r] = am * (acc[fo][fm][r] * c1a[r] + rs * c2a[r]);
      o4.x = ov[0]; o4.y = ov[1]; o4.z = ov[2]; o4.w = ov[3];
      *(float4*)(out + (size_t)b * NTOT + nb) = o4;
    }
  }
}

// ---------------------------------------------------------------------------
// LN-fused GEMM, fp32 output (for q projection).
// ---------------------------------------------------------------------------
__global__ __launch_bounds__(256)
void ln_gemm_f32(const float* __restrict__ A, const float* __restrict__ mean,
                 const float* __restrict__ rstd, const float* __restrict__ g,
                 const float* __restrict__ bln, const float* __restrict__ W,
                 const float* __restrict__ bias, float* __restrict__ out) {
  __shared__ float As[16][68];
  __shared__ float Ws[16][68];
  const int t = threadIdx.x;
  const int m0 = blockIdx.y << 6, n0 = blockIdx.x << 6;
  const int tm = t >> 4, tn = t & 15;
  const int lr = t >> 2;
  const int lk = (t & 3) << 2;
  const float muL = mean[m0 + lr];
  const float rsL = rstd[m0 + lr];
  float acc[4][4] = {};
  for (int k0 = 0; k0 < DMODEL; k0 += 16) {
    float4 a4 = *(const float4*)(A + (size_t)(m0 + lr) * DMODEL + k0 + lk);
    float4 g4 = *(const float4*)(g + k0 + lk);
    float4 b4 = *(const float4*)(bln + k0 + lk);
    As[lk + 0][lr] = (a4.x - muL) * rsL * g4.x + b4.x;
    As[lk + 1][lr] = (a4.y - muL) * rsL * g4.y + b4.y;
    As[lk + 2][lr] = (a4.z - muL) * rsL * g4.z + b4.z;
    As[lk + 3][lr] = (a4.w - muL) * rsL * g4.w + b4.w;
    float4 w4 = *(const float4*)(W + (size_t)(n0 + lr) * DMODEL + k0 + lk);
    Ws[lk + 0][lr] = w4.x;
    Ws[lk + 1][lr] = w4.y;
    Ws[lk + 2][lr] = w4.z;
    Ws[lk + 3][lr] = w4.w;
    __syncthreads();
#pragma unroll
    for (int kk = 0; kk < 16; kk++) {
      const float4 av = *(const float4*)(&As[kk][tm * 4]);
      const float4 bv = *(const float4*)(&Ws[kk][tn * 4]);
      const float a[4] = {av.x, av.y, av.z, av.w};
      const float b[4] = {bv.x, bv.y, bv.z, bv.w};
#pragma unroll
      for (int i = 0; i < 4; i++)
#pragma unroll
        for (int j = 0; j < 4; j++) acc[i][j] += a[i] * b[j];
    }
    __syncthreads();
  }
  const float4 bia = *(const float4*)(bias + n0 + tn * 4);
  const float bb[4] = {bia.x, bia.y, bia.z, bia.w};
#pragma unroll
  for (int i = 0; i < 4; i++) {
    const int m = m0 + tm * 4 + i;
    float4 o4;
    o4.x = acc[i][0] + bb[0];
    o4.y = acc[i][1] + bb[1];
    o4.z = acc[i][2] + bb[2];
    o4.w = acc[i][3] + bb[3];
    *(float4*)(out + (size_t)m * DMODEL + n0 + tn * 4) = o4;
  }
}

// ---------------------------------------------------------------------------
// Plain small GEMM: out = act(A @ W^T + bias [+ add])
// ---------------------------------------------------------------------------
__global__ __launch_bounds__(256)
void gemm_bias(const float* __restrict__ A, const float* __restrict__ W,
               const float* __restrict__ bias, const float* __restrict__ add,
               float* __restrict__ out, int relu) {
  __shared__ float As[16][68];
  __shared__ float Ws[16][68];
  const int t = threadIdx.x;
  const int m0 = blockIdx.y << 6, n0 = blockIdx.x << 6;
  const int tm = t >> 4, tn = t & 15;
  const int lr = t >> 2;
  const int lk = (t & 3) << 2;
  float acc[4][4] = {};
  for (int k0 = 0; k0 < DMODEL; k0 += 16) {
    float4 a4 = *(const float4*)(A + (size_t)(m0 + lr) * DMODEL + k0 + lk);
    As[lk + 0][lr] = a4.x;
    As[lk + 1][lr] = a4.y;
    As[lk + 2][lr] = a4.z;
    As[lk + 3][lr] = a4.w;
    float4 w4 = *(const float4*)(W + (size_t)(n0 + lr) * DMODEL + k0 + lk);
    Ws[lk + 0][lr] = w4.x;
    Ws[lk + 1][lr] = w4.y;
    Ws[lk + 2][lr] = w4.z;
    Ws[lk + 3][lr] = w4.w;
    __syncthreads();
#pragma unroll
    for (int kk = 0; kk < 16; kk++) {
      const float4 av = *(const float4*)(&As[kk][tm * 4]);
      const float4 bv = *(const float4*)(&Ws[kk][tn * 4]);
      const float a[4] = {av.x, av.y, av.z, av.w};
      const float b[4] = {bv.x, bv.y, bv.z, bv.w};
#pragma unroll
      for (int i = 0; i < 4; i++)
#pragma unroll
        for (int j = 0; j < 4; j++) acc[i][j] += a[i] * b[j];
    }
    __syncthreads();
  }
  const float4 bia = *(const float4*)(bias + n0 + tn * 4);
  const float bb[4] = {bia.x, bia.y, bia.z, bia.w};
#pragma unroll
  for (int i = 0; i < 4; i++) {
    const int m = m0 + tm * 4 + i;
    float v[4];
#pragma unroll
    for (int j = 0; j < 4; j++) v[j] = acc[i][j] + bb[j];
    if (add) {
      const float4 a4 = *(const float4*)(add + (size_t)m * DMODEL + n0 + tn * 4);
      v[0] += a4.x; v[1] += a4.y; v[2] += a4.z; v[3] += a4.w;
    }
    if (relu) {
#pragma unroll
      for (int j = 0; j < 4; j++) v[j] = fmaxf(v[j], 0.f);
    }
    float4 o4 = {v[0], v[1], v[2], v[3]};
    *(float4*)(out + (size_t)m * DMODEL + n0 + tn * 4) = o4;
  }
}

// ---------------------------------------------------------------------------
// Split xi (fp32) into beta-scaled fp16 hi/lo pair.
// ---------------------------------------------------------------------------
__global__ __launch_bounds__(256)
void split_xi_k(const float* __restrict__ xi, f16* __restrict__ hi,
                f16* __restrict__ lo) {
  const int i = blockIdx.x * 256 + threadIdx.x;  // over float4s: 24576 total
  float4 v = ((const float4*)xi)[i];
  float s[4] = {v.x * BETA, v.y * BETA, v.z * BETA, v.w * BETA};
  f16x4 h4, l4;
#pragma unroll
  for (int j = 0; j < 4; j++) {
    f16 h = (f16)s[j];
    h4[j] = h;
    l4[j] = (f16)(s[j] - (float)h);
  }
  ((f16x4*)hi)[i] = h4;
  ((f16x4*)lo)[i] = l4;
}

// ---------------------------------------------------------------------------
// MFMA flash attention round, full hi/lo precision (fp32-accurate).
// v5: 3-buffer global_load_lds pipeline with COUNTED vmcnt (T4). Each wave
// issues 3 DMA chunks per tile; at the per-iter barrier we wait vmcnt(3) —
// tile t+1 resident, tile t+2's loads stay in flight (never drain to 0 in
// the main loop). Raw s_barrier replaces __syncthreads' vmcnt(0) drain.
// Hazards: per-wave vmcnt + barrier join => all 12 chunks of t+1 resident;
// buffer recycle (t-1 -> t+2) separated by one barrier; P LDS is wave-
// private (no cross-wave lgkm dep at barrier). Operand math unchanged.
// ---------------------------------------------------------------------------
#define FCHUNK 64
#define FROWS (NTOT / FCHUNK)  // 512

__global__ __launch_bounds__(256)
void flash_round(const f16* __restrict__ k_hi, const f16* __restrict__ k_lo,
                 const f16* __restrict__ pvT_hi, const f16* __restrict__ pvT_lo,
                 const f16* __restrict__ xi_hi, const f16* __restrict__ xi_lo,
                 float* __restrict__ part_ml, float* __restrict__ part_o) {
  const int h = blockIdx.y, chunk = blockIdx.x;
  const int tid = threadIdx.x, w = tid >> 6, lane = tid & 63;
  const int l15 = lane & 15, lq = lane >> 4;
  const int b0 = w * 32;

  // stage[buf]: f16 offsets 0..3071 = krow [tsel][32 n][48 d];
  //             3072..6143 = ptT [tsel][48 d][32 n] (chunk-swizzled)
  __shared__ __align__(16) f16 stage[3][6144];
  __shared__ __align__(16) f16 pHi[4][32][40];
  __shared__ __align__(16) f16 pLo[4][32][40];

  const int nbase = chunk * FROWS;

  // 12 issue slots (3 per wave); slot s covers 16B-chunks [s*64, s*64+64)
  const f16* gsrc[3];
  int gstep[3];
#pragma unroll
  for (int g = 0; g < 3; g++) {
    const int s = w * 3 + g;
    const int ci = s * 64 + lane;
    if (s < 6) {  // krow: chunk = tsel*192 + r*6 + dc
      const int tsel = ci / 192, rem = ci % 192;
      const int r = rem / 6, dc = rem % 6;
      gsrc[g] = (tsel ? k_lo : k_hi) + (size_t)(nbase + r) * DMODEL + h * DH + dc * 8;
      gstep[g] = 32 * DMODEL;
    } else {      // ptT: chunk = 384 + tsel*192 + d*4 + pc; logical nc = pc^(d&3)
      const int j = ci - 384;
      const int tsel = j / 192, rem = j % 192;
      const int d = rem / 4, pc = rem % 4;
      const int nc = pc ^ (d & 3);
      gsrc[g] = (tsel ? pvT_lo : pvT_hi) + (size_t)(h * DH + d) * NTOT + nbase + nc * 8;
      gstep[g] = 32;
    }
  }

  const f16x8 zf = {};
  f16x8 xqh[2][2], xql[2][2];
#pragma unroll
  for (int bt = 0; bt < 2; bt++) {
    const size_t xoff = (size_t)(b0 + bt * 16 + l15) * DMODEL + h * DH;
    xqh[bt][0] = *(const f16x8*)(xi_hi + xoff + lq * 8);
    xql[bt][0] = *(const f16x8*)(xi_lo + xoff + lq * 8);
    const size_t xo1 = xoff + 32 + (lq & 1) * 8;
    f16x8 th = *(const f16x8*)(xi_hi + xo1);
    f16x8 tl = *(const f16x8*)(xi_lo + xo1);
    xqh[bt][1] = (lq < 2) ? th : zf;
    xql[bt][1] = (lq < 2) ? tl : zf;
  }

  float m[2] = {-1e30f, -1e30f}, lsum[2] = {0.f, 0.f};
  f32x4 O[3][2];
#pragma unroll
  for (int mt = 0; mt < 3; mt++)
#pragma unroll
    for (int bt = 0; bt < 2; bt++)
#pragma unroll
      for (int j = 0; j < 4; j++) O[mt][bt][j] = 0.f;

  // prologue: DMA tiles 0 and 1 into bufs 0 and 1; wait only for tile 0
#pragma unroll
  for (int b = 0; b < 2; b++) {
#pragma unroll
    for (int g = 0; g < 3; g++) {
      __builtin_amdgcn_global_load_lds(
          (__attribute__((address_space(1))) void*)gsrc[g],
          (__attribute__((address_space(3))) void*)&stage[b][(w * 3 + g) * 512],
          16, 0, 0);
      gsrc[g] += gstep[g];
    }
  }
  __asm__ volatile("s_waitcnt vmcnt(3)" ::: "memory");  // tile 0 resident
  __builtin_amdgcn_s_barrier();
  __asm__ volatile("" ::: "memory");

  int cur = 0, nxt = 2;
  for (int it = 0; it < 16; it++) {
    // issue tile it+2 into the recycled buffer (last read at iter it-1)
    if (it < 14) {
#pragma unroll
      for (int g = 0; g < 3; g++) {
        __builtin_amdgcn_global_load_lds(
            (__attribute__((address_space(1))) void*)gsrc[g],
            (__attribute__((address_space(3))) void*)&stage[nxt][(w * 3 + g) * 512],
            16, 0, 0);
        gsrc[g] += gstep[g];
      }
    }
    const f16* st = stage[cur];

    f16x8 akh[2][2], akl[2][2];
#pragma unroll
    for (int nt = 0; nt < 2; nt++) {
      const int row = nt * 16 + l15;
      akh[nt][0] = *(const f16x8*)&st[row * 48 + lq * 8];
      akl[nt][0] = *(const f16x8*)&st[1536 + row * 48 + lq * 8];
      f16x8 t0 = *(const f16x8*)&st[row * 48 + 32 + (lq & 1) * 8];
      f16x8 t1 = *(const f16x8*)&st[1536 + row * 48 + 32 + (lq & 1) * 8];
      akh[nt][1] = (lq < 2) ? t0 : zf;
      akl[nt][1] = (lq < 2) ? t1 : zf;
    }
    f32x4 S[2][2];
#pragma unroll
    for (int nt = 0; nt < 2; nt++)
#pragma unroll
      for (int bt = 0; bt < 2; bt++) {
        f32x4 s = {};
        s = __builtin_amdgcn_mfma_f32_16x16x32_f16(akh[nt][0], xqh[bt][0], s, 0, 0, 0);
        s = __builtin_amdgcn_mfma_f32_16x16x32_f16(akh[nt][1], xqh[bt][1], s, 0, 0, 0);
        s = __builtin_amdgcn_mfma_f32_16x16x32_f16(akh[nt][0], xql[bt][0], s, 0, 0, 0);
        s = __builtin_amdgcn_mfma_f32_16x16x32_f16(akh[nt][1], xql[bt][1], s, 0, 0, 0);
        s = __builtin_amdgcn_mfma_f32_16x16x32_f16(akl[nt][0], xqh[bt][0], s, 0, 0, 0);
        s = __builtin_amdgcn_mfma_f32_16x16x32_f16(akl[nt][1], xqh[bt][1], s, 0, 0, 0);
        S[nt][bt] = s;
      }
    float sc[2];
#pragma unroll
    for (int bt = 0; bt < 2; bt++) {
      float mx = S[0][bt][0];
#pragma unroll
      for (int r = 1; r < 4; r++) mx = fmaxf(mx, S[0][bt][r]);
#pragma unroll
      for (int r = 0; r < 4; r++) mx = fmaxf(mx, S[1][bt][r]);
      mx = fmaxf(mx, __shfl_xor(mx, 16));
      mx = fmaxf(mx, __shfl_xor(mx, 32));
      const float mnew = fmaxf(m[bt], mx);
      sc[bt] = __expf(m[bt] - mnew);
      float ps = 0.f;
#pragma unroll
      for (int nt = 0; nt < 2; nt++) {
        f16x4 ph, pl;
#pragma unroll
        for (int r = 0; r < 4; r++) {
          const float p = __expf(S[nt][bt][r] - mnew);
          ps += p;
          const f16 hh = (f16)p;
          ph[r] = hh;
          pl[r] = (f16)(p - (float)hh);
        }
        *(f16x4*)&pHi[w][bt * 16 + l15][nt * 16 + lq * 4] = ph;
        *(f16x4*)&pLo[w][bt * 16 + l15][nt * 16 + lq * 4] = pl;
      }
      ps += __shfl_xor(ps, 16);
      ps += __shfl_xor(ps, 32);
      lsum[bt] = lsum[bt] * sc[bt] + ps;
      m[bt] = mnew;
    }
    __asm__ volatile("s_waitcnt lgkmcnt(0)" ::: "memory");
    f16x8 avh[3], avl[3];
#pragma unroll
    for (int mt = 0; mt < 3; mt++) {
      const int d = mt * 16 + l15;
      const int po = (lq ^ (d & 3)) * 8;  // swizzled phys chunk
      avh[mt] = *(const f16x8*)&st[3072 + d * 32 + po];
      avl[mt] = *(const f16x8*)&st[3072 + 1536 + d * 32 + po];
    }
    f16x8 pbh[2], pbl[2];
#pragma unroll
    for (int bt = 0; bt < 2; bt++) {
      pbh[bt] = *(const f16x8*)&pHi[w][bt * 16 + l15][lq * 8];
      pbl[bt] = *(const f16x8*)&pLo[w][bt * 16 + l15][lq * 8];
    }
#pragma unroll
    for (int mt = 0; mt < 3; mt++)
#pragma unroll
      for (int bt = 0; bt < 2; bt++) {
#pragma unroll
        for (int j = 0; j < 4; j++) O[mt][bt][j] *= sc[bt];
        f32x4 o = O[mt][bt];
        o = __builtin_amdgcn_mfma_f32_16x16x32_f16(avh[mt], pbh[bt], o, 0, 0, 0);
        o = __builtin_amdgcn_mfma_f32_16x16x32_f16(avh[mt], pbl[bt], o, 0, 0, 0);
        o = __builtin_amdgcn_mfma_f32_16x16x32_f16(avl[mt], pbh[bt], o, 0, 0, 0);
        O[mt][bt] = o;
      }

    if (it < 15) {
      // counted wait: tile it+1's 3 loads done; tile it+2's may stay in flight
      if (it < 14) __asm__ volatile("s_waitcnt vmcnt(3)" ::: "memory");
      else         __asm__ volatile("s_waitcnt vmcnt(0)" ::: "memory");
      __builtin_amdgcn_s_barrier();
      __asm__ volatile("" ::: "memory");
      cur = (cur == 2) ? 0 : cur + 1;
      nxt = (nxt == 2) ? 0 : nxt + 1;
    }
  }
  const int pc = h * FCHUNK + chunk;
  if (lq == 0) {
#pragma unroll
    for (int bt = 0; bt < 2; bt++) {
      float* pm = part_ml + ((size_t)pc * BSZ + b0 + bt * 16 + l15) * 2;
      pm[0] = m[bt];
      pm[1] = lsum[bt];
    }
  }
#pragma unroll
  for (int mt = 0; mt < 3; mt++)
#pragma unroll
    for (int bt = 0; bt < 2; bt++) {
      float* po = part_o + ((size_t)pc * BSZ + b0 + bt * 16 + l15) * 48 +
                  mt * 16 + lq * 4;
      *(f32x4*)po = O[mt][bt];
    }
}

// ---------------------------------------------------------------------------
// Combine 64 chunk-partials per (b,h). Grid = B*H blocks of 64 threads.
// ---------------------------------------------------------------------------
__global__ __launch_bounds__(64)
void hopfield_combine(const float* __restrict__ part_ml,
                      const float* __restrict__ part_o, float* __restrict__ dst) {
  const int bh = blockIdx.x;  // h*128 + b
  const int h = bh >> 7, b = bh & 127;
  const int c = threadIdx.x;
  __shared__ float w[64];
  const float* pm = part_ml + ((size_t)(h * 64 + c) * BSZ + b) * 2;
  const float mp = pm[0];
  const float lp = pm[1];
  float M = mp;
#pragma unroll
  for (int off = 32; off; off >>= 1) M = fmaxf(M, __shfl_xor(M, off));
  const float wp = __expf(mp - M);
  w[c] = wp;
  float L = lp * wp;
#pragma unroll
  for (int off = 32; off; off >>= 1) L += __shfl_xor(L, off);
  __syncthreads();
  if (c < DH) {
    float o = 0.f;
    for (int p = 0; p < 64; p++)
      o += part_o[((size_t)(h * 64 + p) * BSZ + b) * 48 + c] * w[p];
    dst[(size_t)b * DMODEL + h * DH + c] = o / L;
  }
}

// ---------------------------------------------------------------------------
// Top-4 per row with jax tie-breaking (lower index first).
// ---------------------------------------------------------------------------
__global__ __launch_bounds__(256)
void topk_kernel(const float* __restrict__ logits, float* __restrict__ outIdx) {
  const int b = blockIdx.x;
  const int t = threadIdx.x;
  const float* row = logits + (size_t)b * NTOT;
  float v[4] = {-1e30f, -1e30f, -1e30f, -1e30f};
  int id[4] = {0x7fffffff, 0x7fffffff, 0x7fffffff, 0x7fffffff};
  for (int n = t; n < NTOT; n += 256) {
    const float x = row[n];
    if (x > v[3]) {
      v[3] = x; id[3] = n;
#pragma unroll
      for (int s = 3; s > 0; s--) {
        const bool sw = (v[s] > v[s - 1]) || (v[s] == v[s - 1] && id[s] < id[s - 1]);
        if (sw) {
          float tv = v[s]; v[s] = v[s - 1]; v[s - 1] = tv;
          int ti = id[s]; id[s] = id[s - 1]; id[s - 1] = ti;
        }
      }
    }
  }
  __shared__ float sv[256][4];
  __shared__ int si[256][4];
#pragma unroll
  for (int j = 0; j < 4; j++) { sv[t][j] = v[j]; si[t][j] = id[j]; }
  for (int str = 128; str >= 1; str >>= 1) {
    __syncthreads();
    if (t < str) {
      float a[4], c[4];
      int ai[4], ci[4];
#pragma unroll
      for (int j = 0; j < 4; j++) {
        a[j] = sv[t][j]; ai[j] = si[t][j];
        c[j] = sv[t + str][j]; ci[j] = si[t + str][j];
      }
      float rv[4]; int ri[4];
      int p = 0, q = 0;
#pragma unroll
      for (int oo = 0; oo < 4; oo++) {
        const bool ta = (a[p] > c[q]) || (a[p] == c[q] && ai[p] < ci[q]);
        if (ta) { rv[oo] = a[p]; ri[oo] = ai[p]; p++; }
        else    { rv[oo] = c[q]; ri[oo] = ci[q]; q++; }
      }
#pragma unroll
      for (int j = 0; j < 4; j++) { sv[t][j] = rv[j]; si[t][j] = ri[j]; }
    }
  }
  if (t == 0) {
#pragma unroll
    for (int j = 0; j < 4; j++) outIdx[b * 4 + j] = (float)si[0][j];
  }
}

// ---------------------------------------------------------------------------
extern "C" void kernel_launch(void* const* d_in, const int* in_sizes, int n_in,
                              void* d_out, int out_size, void* d_ws, size_t ws_size,
                              hipStream_t stream) {
  const float* qe    = (const float*)d_in[0];
  const float* mb    = (const float*)d_in[1];
  const float* ln_kg = (const float*)d_in[2];
  const float* ln_kb = (const float*)d_in[3];
  const float* ln_qg = (const float*)d_in[4];
  const float* ln_qb = (const float*)d_in[5];
  const float* ln_vg = (const float*)d_in[6];
  const float* ln_vb = (const float*)d_in[7];
  const float* Wq = (const float*)d_in[8];
  const float* bq = (const float*)d_in[9];
  const float* Wk = (const float*)d_in[10];
  const float* bk = (const float*)d_in[11];
  const float* Wv = (const float*)d_in[12];
  const float* bv = (const float*)d_in[13];
  const float* Wo = (const float*)d_in[14];
  const float* bo = (const float*)d_in[15];
  const float* W1 = (const float*)d_in[16];
  const float* b1 = (const float*)d_in[17];
  const float* W2 = (const float*)d_in[18];
  const float* b2 = (const float*)d_in[19];

  float* out = (float*)d_out;  // [0..511] top indices (as float), then logits
  float* logits = out + BSZ * 4;

  float* ws = (float*)d_ws;
  size_t off = 0;
  auto alloc = [&](size_t n) { float* p = ws + off; off += n; return p; };
  const size_t ND2 = (size_t)NTOT * DMODEL / 2;  // one fp16 N*D buffer, in floats
  float* c1      = alloc(NTOT);
  float* c2      = alloc(NTOT);
  float* q_mean  = alloc(128);
  float* q_rstd  = alloc(128);
  float* rq_inv  = alloc(128);
  float* rq_sum  = alloc(128);
  float* pad_    = alloc(256);
  f16* k_hi  = (f16*)alloc(ND2);  // [N][768] row-major (QK operand)
  f16* k_lo  = (f16*)alloc(ND2);
  f16* T_hi  = (f16*)alloc(ND2);  // [768][N]: K^T for rounds 0-4, then V^T
  f16* T_lo  = (f16*)alloc(ND2);
  f16* nh_hi = (f16*)alloc(ND2);  // normalized mb, fp16 hi/lo
  f16* nh_lo = (f16*)alloc(ND2);
  float* part_ml = alloc((size_t)NHEAD * FCHUNK * BSZ * 2);
  float* part_o  = alloc((size_t)NHEAD * FCHUNK * BSZ * 48);
  float* xi   = alloc((size_t)BSZ * DMODEL);
  float* conv = alloc((size_t)BSZ * DMODEL);
  float* comb = alloc((size_t)BSZ * DMODEL);
  float* h1   = alloc((size_t)BSZ * DMODEL);
  f16* xi_hi = (f16*)alloc((size_t)BSZ * DMODEL / 2);
  f16* xi_lo = (f16*)alloc((size_t)BSZ * DMODEL / 2);
  f16* rq_hi = (f16*)alloc((size_t)BSZ * DMODEL / 2);
  f16* rq_lo = (f16*)alloc((size_t)BSZ * DMODEL / 2);
  f16* Wc_hi = (f16*)alloc((size_t)2 * DMODEL * DMODEL / 2);  // [1536][768]
  f16* Wc_lo = (f16*)alloc((size_t)2 * DMODEL * DMODEL / 2);
  float* biasc = alloc(2 * DMODEL);
  (void)ws_size; (void)in_sizes; (void)n_in; (void)out_size; (void)pad_;

  // 1. stats (q) + fused stats/normalize/split (mb) + W prep
  row_stats<<<BSZ / 4, 256, 0, stream>>>(qe, BSZ, q_mean, q_rstd, nullptr);
  stats_norm_mb<<<NTOT / 4, 256, 0, stream>>>(mb, nh_hi, nh_lo, c1, c2);
  prep_w<<<2 * DMODEL / 4, 256, 0, stream>>>(Wk, bk, ln_kg, ln_kb,
                                             Wv, bv, ln_vg, ln_vb,
                                             Wc_hi, Wc_lo, biasc);

  // 2. K-half projection (k row-major + K^T into T); q (xi) fp32
  proj_mfma<<<dim3(DMODEL / 128, NTOT / 128), 256, 0, stream>>>(
      nh_hi, nh_lo, Wc_hi, Wc_lo, biasc, k_hi, k_lo, T_hi, T_lo, 0);
  ln_gemm_f32<<<dim3(DMODEL / 64, BSZ / 64), 256, 0, stream>>>(
      qe, q_mean, q_rstd, ln_qg, ln_qb, Wq, bq, xi);

  // 3. Hopfield rounds 0-4 (PV source = K^T in T)
  for (int r = 0; r < 5; r++) {
    split_xi_k<<<96, 256, 0, stream>>>(xi, xi_hi, xi_lo);
    flash_round<<<dim3(FCHUNK, NHEAD), 256, 0, stream>>>(
        k_hi, k_lo, T_hi, T_lo, xi_hi, xi_lo, part_ml, part_o);
    hopfield_combine<<<BSZ * NHEAD, 64, 0, stream>>>(part_ml, part_o, xi);
  }

  // 3b. V-half projection: writes V^T over the (now dead) K^T buffer
  proj_mfma<<<dim3(DMODEL / 128, NTOT / 128), 256, 0, stream>>>(
      nh_hi, nh_lo, Wc_hi, Wc_lo, biasc, k_hi, k_lo, T_hi, T_lo, DMODEL);

  // 3c. readout round (PV source = V^T in T)
  split_xi_k<<<96, 256, 0, stream>>>(xi, xi_hi, xi_lo);
  flash_round<<<dim3(FCHUNK, NHEAD), 256, 0, stream>>>(
      k_hi, k_lo, T_hi, T_lo, xi_hi, xi_lo, part_ml, part_o);
  hopfield_combine<<<BSZ * NHEAD, 64, 0, stream>>>(part_ml, part_o, conv);

  // 4. readout MLP
  gemm_bias<<<dim3(DMODEL / 64, BSZ / 64), 256, 0, stream>>>(conv, Wo, bo, qe, comb, 0);
  gemm_bias<<<dim3(DMODEL / 64, BSZ / 64), 256, 0, stream>>>(comb, W1, b1, nullptr, h1, 1);
  float* rq = conv;  // conv dead after comb computed; reuse for rq
  gemm_bias<<<dim3(DMODEL / 64, BSZ / 64), 256, 0, stream>>>(h1, W2, b2, nullptr, rq, 0);

  // 5. cosine logits: split rq, then MFMA over nh with LN-reconstruction fold
  rq_prep<<<BSZ / 4, 256, 0, stream>>>(rq, rq_hi, rq_lo, rq_inv, rq_sum);
  logits_mfma<<<NTOT / 128, 256, 0, stream>>>(nh_hi, nh_lo, rq_hi, rq_lo,
                                              c1, c2, rq_inv, rq_sum, logits);

  // 6. top-4 indices
  topk_kernel<<<BSZ, 256, 0, stream>>>(logits, out);
}

// Round 7
// 1308.901 us; speedup vs baseline: 1.0522x; 1.0339x over previous
//
#include <hip/hip_runtime.h>
#include <math.h>

#define NTOT 32768
#define DMODEL 768
#define BSZ 128
#define NHEAD 16
#define DH 48
#define BETA 0.25f

typedef _Float16 f16;
typedef f16 f16x8 __attribute__((ext_vector_type(8)));
typedef f16 f16x4 __attribute__((ext_vector_type(4)));
typedef float f32x4 __attribute__((ext_vector_type(4)));

// ---------------------------------------------------------------------------
// Row stats: mean, rstd (LN, biased var, eps=1e-5), optional l2inv of raw row.
// ---------------------------------------------------------------------------
__global__ __launch_bounds__(256)
void row_stats(const float* __restrict__ X, int M, float* __restrict__ mean,
               float* __restrict__ rstd, float* __restrict__ l2inv) {
  const int row = blockIdx.x * 4 + (threadIdx.x >> 6);
  const int lane = threadIdx.x & 63;
  if (row >= M) return;
  const float* x = X + (size_t)row * DMODEL;
  float s = 0.f, s2 = 0.f;
  for (int i = lane; i < DMODEL; i += 64) {
    float v = x[i];
    s += v; s2 += v * v;
  }
#pragma unroll
  for (int off = 32; off; off >>= 1) {
    s  += __shfl_xor(s, off);
    s2 += __shfl_xor(s2, off);
  }
  if (lane == 0) {
    float mu = s * (1.f / DMODEL);
    float var = s2 * (1.f / DMODEL) - mu * mu;
    mean[row] = mu;
    rstd[row] = rsqrtf(var + 1e-5f);
    if (l2inv) l2inv[row] = 1.f / fmaxf(sqrtf(s2), 1e-12f);
  }
}

// ---------------------------------------------------------------------------
// Fused: stats over mb row + nh = (mb-mu)*rstd f16 hi/lo + logits fold consts.
// ---------------------------------------------------------------------------
__global__ __launch_bounds__(256)
void stats_norm_mb(const float* __restrict__ mb, f16* __restrict__ nh_hi,
                   f16* __restrict__ nh_lo, float* __restrict__ c1,
                   float* __restrict__ c2) {
  const int row = blockIdx.x * 4 + (threadIdx.x >> 6);
  const int lane = threadIdx.x & 63;
  const float* x = mb + (size_t)row * DMODEL;
  float v[12];
  float s = 0.f, s2 = 0.f;
#pragma unroll
  for (int j = 0; j < 3; j++) {
    const float4 v4 = *(const float4*)(x + lane * 4 + j * 256);
    v[j * 4 + 0] = v4.x; v[j * 4 + 1] = v4.y;
    v[j * 4 + 2] = v4.z; v[j * 4 + 3] = v4.w;
    s += v4.x + v4.y + v4.z + v4.w;
    s2 += v4.x * v4.x + v4.y * v4.y + v4.z * v4.z + v4.w * v4.w;
  }
#pragma unroll
  for (int off = 32; off; off >>= 1) {
    s  += __shfl_xor(s, off);
    s2 += __shfl_xor(s2, off);
  }
  const float mu = s * (1.f / DMODEL);
  const float var = s2 * (1.f / DMODEL) - mu * mu;
  const float istd = sqrtf(var + 1e-5f);
  const float rs = 1.f / istd;
  f16* oh = nh_hi + (size_t)row * DMODEL;
  f16* ol = nh_lo + (size_t)row * DMODEL;
#pragma unroll
  for (int j = 0; j < 3; j++) {
    f16x4 h4, l4;
#pragma unroll
    for (int q = 0; q < 4; q++) {
      const float sv = (v[j * 4 + q] - mu) * rs;
      const f16 h = (f16)sv;
      h4[q] = h;
      l4[q] = (f16)(sv - (float)h);
    }
    *(f16x4*)(oh + lane * 4 + j * 256) = h4;
    *(f16x4*)(ol + lane * 4 + j * 256) = l4;
  }
  if (lane == 0) {
    const float l2i = 1.f / fmaxf(sqrtf(s2), 1e-12f);
    c1[row] = 20.f * l2i * istd;
    c2[row] = 20.f * l2i * mu;
  }
}

// ---------------------------------------------------------------------------
// rq_prep: per-row sum, l2inv, and f16 hi/lo split of rq (128 rows).
// ---------------------------------------------------------------------------
__global__ __launch_bounds__(256)
void rq_prep(const float* __restrict__ rq, f16* __restrict__ hi,
             f16* __restrict__ lo, float* __restrict__ ainv,
             float* __restrict__ rqsum) {
  const int row = blockIdx.x * 4 + (threadIdx.x >> 6);
  const int lane = threadIdx.x & 63;
  const float* x = rq + (size_t)row * DMODEL;
  f16* oh = hi + (size_t)row * DMODEL;
  f16* ol = lo + (size_t)row * DMODEL;
  float s = 0.f, s2 = 0.f;
#pragma unroll
  for (int j = 0; j < 3; j++) {
    const int d = lane * 4 + j * 256;
    const float4 v4 = *(const float4*)(x + d);
    const float vv[4] = {v4.x, v4.y, v4.z, v4.w};
    f16x4 h4, l4;
#pragma unroll
    for (int q = 0; q < 4; q++) {
      s += vv[q]; s2 += vv[q] * vv[q];
      const f16 h = (f16)vv[q];
      h4[q] = h;
      l4[q] = (f16)(vv[q] - (float)h);
    }
    *(f16x4*)(oh + d) = h4;
    *(f16x4*)(ol + d) = l4;
  }
#pragma unroll
  for (int off = 32; off; off >>= 1) {
    s  += __shfl_xor(s, off);
    s2 += __shfl_xor(s2, off);
  }
  if (lane == 0) {
    rqsum[row] = s;
    ainv[row] = 1.f / fmaxf(sqrtf(s2), 1e-12f);
  }
}

// ---------------------------------------------------------------------------
// prep_w: combined W' (o<768: g_k*Wk rows; o>=768: g_v*Wv rows), scaled x16,
// split fp16 hi/lo; biasc[o] = bias[o] + sum_d bln[d]*W[o,d].
// ---------------------------------------------------------------------------
__global__ __launch_bounds__(256)
void prep_w(const float* __restrict__ Wk, const float* __restrict__ bk,
            const float* __restrict__ gk, const float* __restrict__ blnk,
            const float* __restrict__ Wv, const float* __restrict__ bv,
            const float* __restrict__ gv, const float* __restrict__ blnv,
            f16* __restrict__ Wc_hi, f16* __restrict__ Wc_lo,
            float* __restrict__ biasc) {
  const int o = blockIdx.x * 4 + (threadIdx.x >> 6);  // 0..1535
  const int lane = threadIdx.x & 63;
  const bool isK = o < DMODEL;
  const float* W = isK ? (Wk + (size_t)o * DMODEL)
                       : (Wv + (size_t)(o - DMODEL) * DMODEL);
  const float* g   = isK ? gk : gv;
  const float* bln = isK ? blnk : blnv;
  float bacc = 0.f;
  for (int d = lane * 4; d < DMODEL; d += 256) {
    const float4 wv = *(const float4*)(W + d);
    const float4 g4 = *(const float4*)(g + d);
    const float4 b4 = *(const float4*)(bln + d);
    bacc += wv.x * b4.x + wv.y * b4.y + wv.z * b4.z + wv.w * b4.w;
    const float sv[4] = {wv.x * g4.x * 16.f, wv.y * g4.y * 16.f,
                         wv.z * g4.z * 16.f, wv.w * g4.w * 16.f};
    f16x4 h4, l4;
#pragma unroll
    for (int j = 0; j < 4; j++) {
      const f16 h = (f16)sv[j];
      h4[j] = h;
      l4[j] = (f16)(sv[j] - (float)h);
    }
    *(f16x4*)(Wc_hi + (size_t)o * DMODEL + d) = h4;
    *(f16x4*)(Wc_lo + (size_t)o * DMODEL + d) = l4;
  }
#pragma unroll
  for (int off = 32; off; off >>= 1) bacc += __shfl_xor(bacc, off);
  if (lane == 0) biasc[o] = (isK ? bk[o] : bv[o - DMODEL]) + bacc;
}

// ---------------------------------------------------------------------------
// Half-projection GEMM via 16x16x32 f16 MFMA, 3-term hi/lo split.
// ---------------------------------------------------------------------------
__global__ __launch_bounds__(256)
void proj_mfma(const f16* __restrict__ nh_hi, const f16* __restrict__ nh_lo,
               const f16* __restrict__ Wc_hi, const f16* __restrict__ Wc_lo,
               const float* __restrict__ biasc,
               f16* __restrict__ k_hi, f16* __restrict__ k_lo,
               f16* __restrict__ T_hi, f16* __restrict__ T_lo, int oc0) {
  __shared__ __align__(16) f16 As[128][64];  // [m][hi/lo-interleaved k]
  __shared__ __align__(16) f16 Bs[128][64];  // [o][...]
  const int t = threadIdx.x;
  const int n0 = oc0 + blockIdx.x * 128;  // global combined o base
  const int m0 = blockIdx.y * 128;
  const int w = t >> 6, lane = t & 63;
  const int l15 = lane & 15, lq = lane >> 4;
  const int wm = w >> 1, wn = w & 1;
  const int sc = (lane & 7) ^ (lane >> 3);
  const int srow = lane >> 3;

  f32x4 acc[4][4];  // [fo][fm]
#pragma unroll
  for (int a = 0; a < 4; a++)
#pragma unroll
    for (int b = 0; b < 4; b++)
#pragma unroll
      for (int r = 0; r < 4; r++) acc[a][b][r] = 0.f;

  for (int k0 = 0; k0 < DMODEL; k0 += 32) {
    __syncthreads();
#pragma unroll
    for (int i = 0; i < 4; i++) {
      const int rb = (w * 4 + i) * 8;
      const f16* asrc = ((sc < 4) ? nh_hi : nh_lo) +
          (size_t)(m0 + rb + srow) * DMODEL + k0 + (sc & 3) * 8;
      __builtin_amdgcn_global_load_lds(
          (__attribute__((address_space(1))) void*)asrc,
          (__attribute__((address_space(3))) void*)&As[rb][0], 16, 0, 0);
      const f16* bsrc = ((sc < 4) ? Wc_hi : Wc_lo) +
          (size_t)(n0 + rb + srow) * DMODEL + k0 + (sc & 3) * 8;
      __builtin_amdgcn_global_load_lds(
          (__attribute__((address_space(1))) void*)bsrc,
          (__attribute__((address_space(3))) void*)&Bs[rb][0], 16, 0, 0);
    }
    __syncthreads();

    f16x8 nhh[4], nhl[4];  // nh (B operand), free = m
#pragma unroll
    for (int fm = 0; fm < 4; fm++) {
      const int row = wm * 64 + fm * 16 + l15;
      const int e = row & 7;
      nhh[fm] = *(const f16x8*)&As[row][(lq ^ e) * 8];
      nhl[fm] = *(const f16x8*)&As[row][((lq + 4) ^ e) * 8];
    }
    f16x8 wh[4], wl[4];  // W' (A operand), free = o
#pragma unroll
    for (int fo = 0; fo < 4; fo++) {
      const int row = wn * 64 + fo * 16 + l15;
      const int e = row & 7;
      wh[fo] = *(const f16x8*)&Bs[row][(lq ^ e) * 8];
      wl[fo] = *(const f16x8*)&Bs[row][((lq + 4) ^ e) * 8];
    }
#pragma unroll
    for (int fo = 0; fo < 4; fo++)
#pragma unroll
      for (int fm = 0; fm < 4; fm++) {
        f32x4 a = acc[fo][fm];
        a = __builtin_amdgcn_mfma_f32_16x16x32_f16(wh[fo], nhh[fm], a, 0, 0, 0);
        a = __builtin_amdgcn_mfma_f32_16x16x32_f16(wh[fo], nhl[fm], a, 0, 0, 0);
        a = __builtin_amdgcn_mfma_f32_16x16x32_f16(wl[fo], nhh[fm], a, 0, 0, 0);
        acc[fo][fm] = a;
      }
  }
  // --- epilogue: /16, +bias, split hi/lo; transposed always, row-major if K ---
  const int oc = n0 + wn * 64;           // global combined o
  const int obase = (oc - oc0) + lq * 4; // local o (0..767)
  const bool wantRow = (oc0 == 0);
#pragma unroll
  for (int fo = 0; fo < 4; fo++) {
    const float4 bb = *(const float4*)(biasc + oc + fo * 16 + lq * 4);
    const float bbv[4] = {bb.x, bb.y, bb.z, bb.w};
    const int o = obase + fo * 16;
#pragma unroll
    for (int fm = 0; fm < 4; fm++) {
      const int mrow = m0 + wm * 64 + fm * 16 + l15;
      f16x4 h4, l4;
#pragma unroll
      for (int r = 0; r < 4; r++) {
        const float v = acc[fo][fm][r] * 0.0625f + bbv[r];
        const f16 h = (f16)v;
        h4[r] = h;
        l4[r] = (f16)(v - (float)h);
      }
      if (wantRow) {
        const size_t moff = (size_t)mrow * DMODEL + o;
        *(f16x4*)(k_hi + moff) = h4;
        *(f16x4*)(k_lo + moff) = l4;
      }
#pragma unroll
      for (int r = 0; r < 4; r++) {
        T_hi[(size_t)(o + r) * NTOT + mrow] = h4[r];
        T_lo[(size_t)(o + r) * NTOT + mrow] = l4[r];
      }
    }
  }
}

// ---------------------------------------------------------------------------
// logits via MFMA on nh: logits[b,n] = ainv[b]*(dot(nh[n],rq[b])*c1[n]
//                                              + rqsum[b]*c2[n])
// ---------------------------------------------------------------------------
__global__ __launch_bounds__(256)
void logits_mfma(const f16* __restrict__ nh_hi, const f16* __restrict__ nh_lo,
                 const f16* __restrict__ rq_hi, const f16* __restrict__ rq_lo,
                 const float* __restrict__ c1, const float* __restrict__ c2,
                 const float* __restrict__ ainv, const float* __restrict__ rqsum,
                 float* __restrict__ out) {
  __shared__ __align__(16) f16 As[128][64];  // nh tile (A operand, free=n)
  __shared__ __align__(16) f16 Bs[128][64];  // rq (B operand, free=batch)
  const int t = threadIdx.x;
  const int n0 = blockIdx.x * 128;
  const int w = t >> 6, lane = t & 63;
  const int l15 = lane & 15, lq = lane >> 4;
  const int wm = w >> 1, wn = w & 1;  // wm: batch half, wn: n half
  const int sc = (lane & 7) ^ (lane >> 3);
  const int srow = lane >> 3;

  f32x4 acc[4][4];  // [fo(n)][fm(batch)]
#pragma unroll
  for (int a = 0; a < 4; a++)
#pragma unroll
    for (int b = 0; b < 4; b++)
#pragma unroll
      for (int r = 0; r < 4; r++) acc[a][b][r] = 0.f;

  for (int k0 = 0; k0 < DMODEL; k0 += 32) {
    __syncthreads();
#pragma unroll
    for (int i = 0; i < 4; i++) {
      const int rb = (w * 4 + i) * 8;
      const f16* asrc = ((sc < 4) ? nh_hi : nh_lo) +
          (size_t)(n0 + rb + srow) * DMODEL + k0 + (sc & 3) * 8;
      __builtin_amdgcn_global_load_lds(
          (__attribute__((address_space(1))) void*)asrc,
          (__attribute__((address_space(3))) void*)&As[rb][0], 16, 0, 0);
      const f16* bsrc = ((sc < 4) ? rq_hi : rq_lo) +
          (size_t)(rb + srow) * DMODEL + k0 + (sc & 3) * 8;
      __builtin_amdgcn_global_load_lds(
          (__attribute__((address_space(1))) void*)bsrc,
          (__attribute__((address_space(3))) void*)&Bs[rb][0], 16, 0, 0);
    }
    __syncthreads();

    f16x8 ah[4], al[4];  // nh (A operand), free = n
#pragma unroll
    for (int fo = 0; fo < 4; fo++) {
      const int row = wn * 64 + fo * 16 + l15;
      const int e = row & 7;
      ah[fo] = *(const f16x8*)&As[row][(lq ^ e) * 8];
      al[fo] = *(const f16x8*)&As[row][((lq + 4) ^ e) * 8];
    }
    f16x8 bh[4], bl[4];  // rq (B operand), free = batch
#pragma unroll
    for (int fm = 0; fm < 4; fm++) {
      const int row = wm * 64 + fm * 16 + l15;
      const int e = row & 7;
      bh[fm] = *(const f16x8*)&Bs[row][(lq ^ e) * 8];
      bl[fm] = *(const f16x8*)&Bs[row][((lq + 4) ^ e) * 8];
    }
#pragma unroll
    for (int fo = 0; fo < 4; fo++)
#pragma unroll
      for (int fm = 0; fm < 4; fm++) {
        f32x4 a = acc[fo][fm];
        a = __builtin_amdgcn_mfma_f32_16x16x32_f16(ah[fo], bh[fm], a, 0, 0, 0);
        a = __builtin_amdgcn_mfma_f32_16x16x32_f16(ah[fo], bl[fm], a, 0, 0, 0);
        a = __builtin_amdgcn_mfma_f32_16x16x32_f16(al[fo], bh[fm], a, 0, 0, 0);
        acc[fo][fm] = a;
      }
  }
#pragma unroll
  for (int fm = 0; fm < 4; fm++) {
    const int b = wm * 64 + fm * 16 + l15;
    const float am = ainv[b];
    const float rs = rqsum[b];
#pragma unroll
    for (int fo = 0; fo < 4; fo++) {
      const int nb = n0 + wn * 64 + fo * 16 + lq * 4;
      const float4 c1v = *(const float4*)(c1 + nb);
      const float4 c2v = *(const float4*)(c2 + nb);
      const float c1a[4] = {c1v.x, c1v.y, c1v.z, c1v.w};
      const float c2a[4] = {c2v.x, c2v.y, c2v.z, c2v.w};
      float4 o4;
      float ov[4];
#pragma unroll
      for (int r = 0; r < 4; r++)
        ov[r] = am * (acc[fo][fm][r] * c1a[r] + rs * c2a[r]);
      o4.x = ov[0]; o4.y = ov[1]; o4.z = ov[2]; o4.w = ov[3];
      *(float4*)(out + (size_t)b * NTOT + nb) = o4;
    }
  }
}

// ---------------------------------------------------------------------------
// LN-fused GEMM, fp32 output (for q projection).
// ---------------------------------------------------------------------------
__global__ __launch_bounds__(256)
void ln_gemm_f32(const float* __restrict__ A, const float* __restrict__ mean,
                 const float* __restrict__ rstd, const float* __restrict__ g,
                 const float* __restrict__ bln, const float* __restrict__ W,
                 const float* __restrict__ bias, float* __restrict__ out) {
  __shared__ float As[16][68];
  __shared__ float Ws[16][68];
  const int t = threadIdx.x;
  const int m0 = blockIdx.y << 6, n0 = blockIdx.x << 6;
  const int tm = t >> 4, tn = t & 15;
  const int lr = t >> 2;
  const int lk = (t & 3) << 2;
  const float muL = mean[m0 + lr];
  const float rsL = rstd[m0 + lr];
  float acc[4][4] = {};
  for (int k0 = 0; k0 < DMODEL; k0 += 16) {
    float4 a4 = *(const float4*)(A + (size_t)(m0 + lr) * DMODEL + k0 + lk);
    float4 g4 = *(const float4*)(g + k0 + lk);
    float4 b4 = *(const float4*)(bln + k0 + lk);
    As[lk + 0][lr] = (a4.x - muL) * rsL * g4.x + b4.x;
    As[lk + 1][lr] = (a4.y - muL) * rsL * g4.y + b4.y;
    As[lk + 2][lr] = (a4.z - muL) * rsL * g4.z + b4.z;
    As[lk + 3][lr] = (a4.w - muL) * rsL * g4.w + b4.w;
    float4 w4 = *(const float4*)(W + (size_t)(n0 + lr) * DMODEL + k0 + lk);
    Ws[lk + 0][lr] = w4.x;
    Ws[lk + 1][lr] = w4.y;
    Ws[lk + 2][lr] = w4.z;
    Ws[lk + 3][lr] = w4.w;
    __syncthreads();
#pragma unroll
    for (int kk = 0; kk < 16; kk++) {
      const float4 av = *(const float4*)(&As[kk][tm * 4]);
      const float4 bv = *(const float4*)(&Ws[kk][tn * 4]);
      const float a[4] = {av.x, av.y, av.z, av.w};
      const float b[4] = {bv.x, bv.y, bv.z, bv.w};
#pragma unroll
      for (int i = 0; i < 4; i++)
#pragma unroll
        for (int j = 0; j < 4; j++) acc[i][j] += a[i] * b[j];
    }
    __syncthreads();
  }
  const float4 bia = *(const float4*)(bias + n0 + tn * 4);
  const float bb[4] = {bia.x, bia.y, bia.z, bia.w};
#pragma unroll
  for (int i = 0; i < 4; i++) {
    const int m = m0 + tm * 4 + i;
    float4 o4;
    o4.x = acc[i][0] + bb[0];
    o4.y = acc[i][1] + bb[1];
    o4.z = acc[i][2] + bb[2];
    o4.w = acc[i][3] + bb[3];
    *(float4*)(out + (size_t)m * DMODEL + n0 + tn * 4) = o4;
  }
}

// ---------------------------------------------------------------------------
// Plain small GEMM: out = act(A @ W^T + bias [+ add])
// ---------------------------------------------------------------------------
__global__ __launch_bounds__(256)
void gemm_bias(const float* __restrict__ A, const float* __restrict__ W,
               const float* __restrict__ bias, const float* __restrict__ add,
               float* __restrict__ out, int relu) {
  __shared__ float As[16][68];
  __shared__ float Ws[16][68];
  const int t = threadIdx.x;
  const int m0 = blockIdx.y << 6, n0 = blockIdx.x << 6;
  const int tm = t >> 4, tn = t & 15;
  const int lr = t >> 2;
  const int lk = (t & 3) << 2;
  float acc[4][4] = {};
  for (int k0 = 0; k0 < DMODEL; k0 += 16) {
    float4 a4 = *(const float4*)(A + (size_t)(m0 + lr) * DMODEL + k0 + lk);
    As[lk + 0][lr] = a4.x;
    As[lk + 1][lr] = a4.y;
    As[lk + 2][lr] = a4.z;
    As[lk + 3][lr] = a4.w;
    float4 w4 = *(const float4*)(W + (size_t)(n0 + lr) * DMODEL + k0 + lk);
    Ws[lk + 0][lr] = w4.x;
    Ws[lk + 1][lr] = w4.y;
    Ws[lk + 2][lr] = w4.z;
    Ws[lk + 3][lr] = w4.w;
    __syncthreads();
#pragma unroll
    for (int kk = 0; kk < 16; kk++) {
      const float4 av = *(const float4*)(&As[kk][tm * 4]);
      const float4 bv = *(const float4*)(&Ws[kk][tn * 4]);
      const float a[4] = {av.x, av.y, av.z, av.w};
      const float b[4] = {bv.x, bv.y, bv.z, bv.w};
#pragma unroll
      for (int i = 0; i < 4; i++)
#pragma unroll
        for (int j = 0; j < 4; j++) acc[i][j] += a[i] * b[j];
    }
    __syncthreads();
  }
  const float4 bia = *(const float4*)(bias + n0 + tn * 4);
  const float bb[4] = {bia.x, bia.y, bia.z, bia.w};
#pragma unroll
  for (int i = 0; i < 4; i++) {
    const int m = m0 + tm * 4 + i;
    float v[4];
#pragma unroll
    for (int j = 0; j < 4; j++) v[j] = acc[i][j] + bb[j];
    if (add) {
      const float4 a4 = *(const float4*)(add + (size_t)m * DMODEL + n0 + tn * 4);
      v[0] += a4.x; v[1] += a4.y; v[2] += a4.z; v[3] += a4.w;
    }
    if (relu) {
#pragma unroll
      for (int j = 0; j < 4; j++) v[j] = fmaxf(v[j], 0.f);
    }
    float4 o4 = {v[0], v[1], v[2], v[3]};
    *(float4*)(out + (size_t)m * DMODEL + n0 + tn * 4) = o4;
  }
}

// ---------------------------------------------------------------------------
// Split xi (fp32) into beta-scaled fp16 hi/lo pair. (Round-0 input only; later
// rounds get the split fused into hopfield_combine.)
// ---------------------------------------------------------------------------
__global__ __launch_bounds__(256)
void split_xi_k(const float* __restrict__ xi, f16* __restrict__ hi,
                f16* __restrict__ lo) {
  const int i = blockIdx.x * 256 + threadIdx.x;  // over float4s: 24576 total
  float4 v = ((const float4*)xi)[i];
  float s[4] = {v.x * BETA, v.y * BETA, v.z * BETA, v.w * BETA};
  f16x4 h4, l4;
#pragma unroll
  for (int j = 0; j < 4; j++) {
    f16 h = (f16)s[j];
    h4[j] = h;
    l4[j] = (f16)(s[j] - (float)h);
  }
  ((f16x4*)hi)[i] = h4;
  ((f16x4*)lo)[i] = l4;
}

// ---------------------------------------------------------------------------
// MFMA flash attention round, full hi/lo precision (fp32-accurate).
// v3+T5: reg-staged T14 async-split (R4's proven-best structure) with
// s_setprio(1) around the QK and PV MFMA clusters (guide T5: helps when
// independent blocks co-resident on a CU are at different phases).
// ---------------------------------------------------------------------------
#define FCHUNK 64
#define FROWS (NTOT / FCHUNK)  // 512

__global__ __launch_bounds__(256)
void flash_round(const f16* __restrict__ k_hi, const f16* __restrict__ k_lo,
                 const f16* __restrict__ pvT_hi, const f16* __restrict__ pvT_lo,
                 const f16* __restrict__ xi_hi, const f16* __restrict__ xi_lo,
                 float* __restrict__ part_ml, float* __restrict__ part_o) {
  const int h = blockIdx.y, chunk = blockIdx.x;
  const int tid = threadIdx.x, w = tid >> 6, lane = tid & 63;
  const int l15 = lane & 15, lq = lane >> 4;
  const int b0 = w * 32;

  __shared__ __align__(16) f16 krow[2][32][56];  // [hi/lo][n][d] (QK operand)
  __shared__ __align__(16) f16 ptT[2][48][40];   // [hi/lo][d][n] (PV operand)
  __shared__ __align__(16) f16 pHi[4][32][40];
  __shared__ __align__(16) f16 pLo[4][32][40];

  const int nbase = chunk * FROWS;

  // staging: 768 16B-chunks (krow 384 + ptT 384), thread owns cc*256+tid
  const f16* ssrc[3];
  f16* sdst[3];
  int sstep[3];
#pragma unroll
  for (int cc = 0; cc < 3; cc++) {
    const int idx = cc * 256 + tid;
    if (idx < 384) {
      const int tsel = idx / 192, q = idx % 192;
      const int r = q / 6, c = q % 6;
      ssrc[cc] = (tsel ? k_lo : k_hi) + (size_t)(nbase + r) * DMODEL + h * DH + c * 8;
      sdst[cc] = &krow[tsel][r][c * 8];
      sstep[cc] = 32 * DMODEL;
    } else {
      const int j = idx - 384;
      const int tsel = j / 192, q = j % 192;
      const int d = q / 4, c = q % 4;
      ssrc[cc] = (tsel ? pvT_lo : pvT_hi) + (size_t)(h * DH + d) * NTOT + nbase + c * 8;
      sdst[cc] = &ptT[tsel][d][c * 8];
      sstep[cc] = 32;
    }
  }

  const f16x8 zf = {};
  f16x8 xqh[2][2], xql[2][2];
#pragma unroll
  for (int bt = 0; bt < 2; bt++) {
    const size_t xoff = (size_t)(b0 + bt * 16 + l15) * DMODEL + h * DH;
    xqh[bt][0] = *(const f16x8*)(xi_hi + xoff + lq * 8);
    xql[bt][0] = *(const f16x8*)(xi_lo + xoff + lq * 8);
    const size_t xo1 = xoff + 32 + (lq & 1) * 8;
    f16x8 th = *(const f16x8*)(xi_hi + xo1);
    f16x8 tl = *(const f16x8*)(xi_lo + xo1);
    xqh[bt][1] = (lq < 2) ? th : zf;
    xql[bt][1] = (lq < 2) ? tl : zf;
  }

  float m[2] = {-1e30f, -1e30f}, lsum[2] = {0.f, 0.f};
  f32x4 O[3][2];
#pragma unroll
  for (int mt = 0; mt < 3; mt++)
#pragma unroll
    for (int bt = 0; bt < 2; bt++)
#pragma unroll
      for (int j = 0; j < 4; j++) O[mt][bt][j] = 0.f;

  // prologue: stage tile 0
  f16x8 stg[3];
#pragma unroll
  for (int cc = 0; cc < 3; cc++) {
    stg[cc] = *(const f16x8*)ssrc[cc];
    ssrc[cc] += sstep[cc];
  }
#pragma unroll
  for (int cc = 0; cc < 3; cc++) *(f16x8*)sdst[cc] = stg[cc];
  __syncthreads();

  for (int it = 0; it < 16; it++) {
    // T14: issue next tile's global loads before compute
    if (it < 15) {
#pragma unroll
      for (int cc = 0; cc < 3; cc++) {
        stg[cc] = *(const f16x8*)ssrc[cc];
        ssrc[cc] += sstep[cc];
      }
    }

    f16x8 akh[2][2], akl[2][2];
#pragma unroll
    for (int nt = 0; nt < 2; nt++) {
      const int row = nt * 16 + l15;
      akh[nt][0] = *(const f16x8*)&krow[0][row][lq * 8];
      akl[nt][0] = *(const f16x8*)&krow[1][row][lq * 8];
      f16x8 t0 = *(const f16x8*)&krow[0][row][32 + (lq & 1) * 8];
      f16x8 t1 = *(const f16x8*)&krow[1][row][32 + (lq & 1) * 8];
      akh[nt][1] = (lq < 2) ? t0 : zf;
      akl[nt][1] = (lq < 2) ? t1 : zf;
    }
    f32x4 S[2][2];
    __builtin_amdgcn_s_setprio(1);
#pragma unroll
    for (int nt = 0; nt < 2; nt++)
#pragma unroll
      for (int bt = 0; bt < 2; bt++) {
        f32x4 s = {};
        s = __builtin_amdgcn_mfma_f32_16x16x32_f16(akh[nt][0], xqh[bt][0], s, 0, 0, 0);
        s = __builtin_amdgcn_mfma_f32_16x16x32_f16(akh[nt][1], xqh[bt][1], s, 0, 0, 0);
        s = __builtin_amdgcn_mfma_f32_16x16x32_f16(akh[nt][0], xql[bt][0], s, 0, 0, 0);
        s = __builtin_amdgcn_mfma_f32_16x16x32_f16(akh[nt][1], xql[bt][1], s, 0, 0, 0);
        s = __builtin_amdgcn_mfma_f32_16x16x32_f16(akl[nt][0], xqh[bt][0], s, 0, 0, 0);
        s = __builtin_amdgcn_mfma_f32_16x16x32_f16(akl[nt][1], xqh[bt][1], s, 0, 0, 0);
        S[nt][bt] = s;
      }
    __builtin_amdgcn_s_setprio(0);
    float sc[2];
#pragma unroll
    for (int bt = 0; bt < 2; bt++) {
      float mx = S[0][bt][0];
#pragma unroll
      for (int r = 1; r < 4; r++) mx = fmaxf(mx, S[0][bt][r]);
#pragma unroll
      for (int r = 0; r < 4; r++) mx = fmaxf(mx, S[1][bt][r]);
      mx = fmaxf(mx, __shfl_xor(mx, 16));
      mx = fmaxf(mx, __shfl_xor(mx, 32));
      const float mnew = fmaxf(m[bt], mx);
      sc[bt] = __expf(m[bt] - mnew);
      float ps = 0.f;
#pragma unroll
      for (int nt = 0; nt < 2; nt++) {
        f16x4 ph, pl;
#pragma unroll
        for (int r = 0; r < 4; r++) {
          const float p = __expf(S[nt][bt][r] - mnew);
          ps += p;
          const f16 hh = (f16)p;
          ph[r] = hh;
          pl[r] = (f16)(p - (float)hh);
        }
        *(f16x4*)&pHi[w][bt * 16 + l15][nt * 16 + lq * 4] = ph;
        *(f16x4*)&pLo[w][bt * 16 + l15][nt * 16 + lq * 4] = pl;
      }
      ps += __shfl_xor(ps, 16);
      ps += __shfl_xor(ps, 32);
      lsum[bt] = lsum[bt] * sc[bt] + ps;
      m[bt] = mnew;
    }
    __asm__ volatile("s_waitcnt lgkmcnt(0)" ::: "memory");
    f16x8 avh[3], avl[3];
#pragma unroll
    for (int mt = 0; mt < 3; mt++) {
      avh[mt] = *(const f16x8*)&ptT[0][mt * 16 + l15][lq * 8];
      avl[mt] = *(const f16x8*)&ptT[1][mt * 16 + l15][lq * 8];
    }
    f16x8 pbh[2], pbl[2];
#pragma unroll
    for (int bt = 0; bt < 2; bt++) {
      pbh[bt] = *(const f16x8*)&pHi[w][bt * 16 + l15][lq * 8];
      pbl[bt] = *(const f16x8*)&pLo[w][bt * 16 + l15][lq * 8];
    }
    __builtin_amdgcn_s_setprio(1);
#pragma unroll
    for (int mt = 0; mt < 3; mt++)
#pragma unroll
      for (int bt = 0; bt < 2; bt++) {
#pragma unroll
        for (int j = 0; j < 4; j++) O[mt][bt][j] *= sc[bt];
        f32x4 o = O[mt][bt];
        o = __builtin_amdgcn_mfma_f32_16x16x32_f16(avh[mt], pbh[bt], o, 0, 0, 0);
        o = __builtin_amdgcn_mfma_f32_16x16x32_f16(avh[mt], pbl[bt], o, 0, 0, 0);
        o = __builtin_amdgcn_mfma_f32_16x16x32_f16(avl[mt], pbh[bt], o, 0, 0, 0);
        O[mt][bt] = o;
      }
    __builtin_amdgcn_s_setprio(0);

    // T14 tail: all waves done reading this tile -> overwrite with next
    if (it < 15) {
      __syncthreads();
#pragma unroll
      for (int cc = 0; cc < 3; cc++) *(f16x8*)sdst[cc] = stg[cc];
      __syncthreads();
    }
  }
  const int pc = h * FCHUNK + chunk;
  if (lq == 0) {
#pragma unroll
    for (int bt = 0; bt < 2; bt++) {
      float* pm = part_ml + ((size_t)pc * BSZ + b0 + bt * 16 + l15) * 2;
      pm[0] = m[bt];
      pm[1] = lsum[bt];
    }
  }
#pragma unroll
  for (int mt = 0; mt < 3; mt++)
#pragma unroll
    for (int bt = 0; bt < 2; bt++) {
      float* po = part_o + ((size_t)pc * BSZ + b0 + bt * 16 + l15) * 48 +
                  mt * 16 + lq * 4;
      *(f32x4*)po = O[mt][bt];
    }
}

// ---------------------------------------------------------------------------
// Combine 64 chunk-partials per (b,h) AND emit the beta-scaled f16 hi/lo
// split of the result (fuses the former split_xi_k for rounds 1..5).
// Grid = B*H blocks of 64 threads.
// ---------------------------------------------------------------------------
__global__ __launch_bounds__(64)
void hopfield_combine(const float* __restrict__ part_ml,
                      const float* __restrict__ part_o, float* __restrict__ dst,
                      f16* __restrict__ nx_hi, f16* __restrict__ nx_lo) {
  const int bh = blockIdx.x;  // h*128 + b
  const int h = bh >> 7, b = bh & 127;
  const int c = threadIdx.x;
  __shared__ float w[64];
  const float* pm = part_ml + ((size_t)(h * 64 + c) * BSZ + b) * 2;
  const float mp = pm[0];
  const float lp = pm[1];
  float M = mp;
#pragma unroll
  for (int off = 32; off; off >>= 1) M = fmaxf(M, __shfl_xor(M, off));
  const float wp = __expf(mp - M);
  w[c] = wp;
  float L = lp * wp;
#pragma unroll
  for (int off = 32; off; off >>= 1) L += __shfl_xor(L, off);
  __syncthreads();
  if (c < DH) {
    float o = 0.f;
    for (int p = 0; p < 64; p++)
      o += part_o[((size_t)(h * 64 + p) * BSZ + b) * 48 + c] * w[p];
    const float val = o / L;
    const size_t di = (size_t)b * DMODEL + h * DH + c;
    dst[di] = val;
    const float s = val * BETA;
    const f16 hh = (f16)s;
    nx_hi[di] = hh;
    nx_lo[di] = (f16)(s - (float)hh);
  }
}

// ---------------------------------------------------------------------------
// Top-4 per row with jax tie-breaking (lower index first).
// ---------------------------------------------------------------------------
__global__ __launch_bounds__(256)
void topk_kernel(const float* __restrict__ logits, float* __restrict__ outIdx) {
  const int b = blockIdx.x;
  const int t = threadIdx.x;
  const float* row = logits + (size_t)b * NTOT;
  float v[4] = {-1e30f, -1e30f, -1e30f, -1e30f};
  int id[4] = {0x7fffffff, 0x7fffffff, 0x7fffffff, 0x7fffffff};
  for (int n = t; n < NTOT; n += 256) {
    const float x = row[n];
    if (x > v[3]) {
      v[3] = x; id[3] = n;
#pragma unroll
      for (int s = 3; s > 0; s--) {
        const bool sw = (v[s] > v[s - 1]) || (v[s] == v[s - 1] && id[s] < id[s - 1]);
        if (sw) {
          float tv = v[s]; v[s] = v[s - 1]; v[s - 1] = tv;
          int ti = id[s]; id[s] = id[s - 1]; id[s - 1] = ti;
        }
      }
    }
  }
  __shared__ float sv[256][4];
  __shared__ int si[256][4];
#pragma unroll
  for (int j = 0; j < 4; j++) { sv[t][j] = v[j]; si[t][j] = id[j]; }
  for (int str = 128; str >= 1; str >>= 1) {
    __syncthreads();
    if (t < str) {
      float a[4], c[4];
      int ai[4], ci[4];
#pragma unroll
      for (int j = 0; j < 4; j++) {
        a[j] = sv[t][j]; ai[j] = si[t][j];
        c[j] = sv[t + str][j]; ci[j] = si[t + str][j];
      }
      float rv[4]; int ri[4];
      int p = 0, q = 0;
#pragma unroll
      for (int oo = 0; oo < 4; oo++) {
        const bool ta = (a[p] > c[q]) || (a[p] == c[q] && ai[p] < ci[q]);
        if (ta) { rv[oo] = a[p]; ri[oo] = ai[p]; p++; }
        else    { rv[oo] = c[q]; ri[oo] = ci[q]; q++; }
      }
#pragma unroll
      for (int j = 0; j < 4; j++) { sv[t][j] = rv[j]; si[t][j] = ri[j]; }
    }
  }
  if (t == 0) {
#pragma unroll
    for (int j = 0; j < 4; j++) outIdx[b * 4 + j] = (float)si[0][j];
  }
}

// ---------------------------------------------------------------------------
extern "C" void kernel_launch(void* const* d_in, const int* in_sizes, int n_in,
                              void* d_out, int out_size, void* d_ws, size_t ws_size,
                              hipStream_t stream) {
  const float* qe    = (const float*)d_in[0];
  const float* mb    = (const float*)d_in[1];
  const float* ln_kg = (const float*)d_in[2];
  const float* ln_kb = (const float*)d_in[3];
  const float* ln_qg = (const float*)d_in[4];
  const float* ln_qb = (const float*)d_in[5];
  const float* ln_vg = (const float*)d_in[6];
  const float* ln_vb = (const float*)d_in[7];
  const float* Wq = (const float*)d_in[8];
  const float* bq = (const float*)d_in[9];
  const float* Wk = (const float*)d_in[10];
  const float* bk = (const float*)d_in[11];
  const float* Wv = (const float*)d_in[12];
  const float* bv = (const float*)d_in[13];
  const float* Wo = (const float*)d_in[14];
  const float* bo = (const float*)d_in[15];
  const float* W1 = (const float*)d_in[16];
  const float* b1 = (const float*)d_in[17];
  const float* W2 = (const float*)d_in[18];
  const float* b2 = (const float*)d_in[19];

  float* out = (float*)d_out;  // [0..511] top indices (as float), then logits
  float* logits = out + BSZ * 4;

  float* ws = (float*)d_ws;
  size_t off = 0;
  auto alloc = [&](size_t n) { float* p = ws + off; off += n; return p; };
  const size_t ND2 = (size_t)NTOT * DMODEL / 2;  // one fp16 N*D buffer, in floats
  float* c1      = alloc(NTOT);
  float* c2      = alloc(NTOT);
  float* q_mean  = alloc(128);
  float* q_rstd  = alloc(128);
  float* rq_inv  = alloc(128);
  float* rq_sum  = alloc(128);
  float* pad_    = alloc(256);
  f16* k_hi  = (f16*)alloc(ND2);  // [N][768] row-major (QK operand)
  f16* k_lo  = (f16*)alloc(ND2);
  f16* T_hi  = (f16*)alloc(ND2);  // [768][N]: K^T for rounds 0-4, then V^T
  f16* T_lo  = (f16*)alloc(ND2);
  f16* nh_hi = (f16*)alloc(ND2);  // normalized mb, fp16 hi/lo
  f16* nh_lo = (f16*)alloc(ND2);
  float* part_ml = alloc((size_t)NHEAD * FCHUNK * BSZ * 2);
  float* part_o  = alloc((size_t)NHEAD * FCHUNK * BSZ * 48);
  float* xi   = alloc((size_t)BSZ * DMODEL);
  float* conv = alloc((size_t)BSZ * DMODEL);
  float* comb = alloc((size_t)BSZ * DMODEL);
  float* h1   = alloc((size_t)BSZ * DMODEL);
  f16* xi_hi = (f16*)alloc((size_t)BSZ * DMODEL / 2);
  f16* xi_lo = (f16*)alloc((size_t)BSZ * DMODEL / 2);
  f16* rq_hi = (f16*)alloc((size_t)BSZ * DMODEL / 2);
  f16* rq_lo = (f16*)alloc((size_t)BSZ * DMODEL / 2);
  f16* Wc_hi = (f16*)alloc((size_t)2 * DMODEL * DMODEL / 2);  // [1536][768]
  f16* Wc_lo = (f16*)alloc((size_t)2 * DMODEL * DMODEL / 2);
  float* biasc = alloc(2 * DMODEL);
  (void)ws_size; (void)in_sizes; (void)n_in; (void)out_size; (void)pad_;

  // 1. stats (q) + fused stats/normalize/split (mb) + W prep
  row_stats<<<BSZ / 4, 256, 0, stream>>>(qe, BSZ, q_mean, q_rstd, nullptr);
  stats_norm_mb<<<NTOT / 4, 256, 0, stream>>>(mb, nh_hi, nh_lo, c1, c2);
  prep_w<<<2 * DMODEL / 4, 256, 0, stream>>>(Wk, bk, ln_kg, ln_kb,
                                             Wv, bv, ln_vg, ln_vb,
                                             Wc_hi, Wc_lo, biasc);

  // 2. K-half projection (k row-major + K^T into T); q (xi) fp32
  proj_mfma<<<dim3(DMODEL / 128, NTOT / 128), 256, 0, stream>>>(
      nh_hi, nh_lo, Wc_hi, Wc_lo, biasc, k_hi, k_lo, T_hi, T_lo, 0);
  ln_gemm_f32<<<dim3(DMODEL / 64, BSZ / 64), 256, 0, stream>>>(
      qe, q_mean, q_rstd, ln_qg, ln_qb, Wq, bq, xi);

  // 3. Hopfield rounds 0-4 (PV source = K^T in T); split fused into combine
  split_xi_k<<<96, 256, 0, stream>>>(xi, xi_hi, xi_lo);
  for (int r = 0; r < 5; r++) {
    flash_round<<<dim3(FCHUNK, NHEAD), 256, 0, stream>>>(
        k_hi, k_lo, T_hi, T_lo, xi_hi, xi_lo, part_ml, part_o);
    hopfield_combine<<<BSZ * NHEAD, 64, 0, stream>>>(part_ml, part_o, xi,
                                                     xi_hi, xi_lo);
  }

  // 3b. V-half projection: writes V^T over the (now dead) K^T buffer
  proj_mfma<<<dim3(DMODEL / 128, NTOT / 128), 256, 0, stream>>>(
      nh_hi, nh_lo, Wc_hi, Wc_lo, biasc, k_hi, k_lo, T_hi, T_lo, DMODEL);

  // 3c. readout round (PV source = V^T in T); xi split comes from round 4
  flash_round<<<dim3(FCHUNK, NHEAD), 256, 0, stream>>>(
      k_hi, k_lo, T_hi, T_lo, xi_hi, xi_lo, part_ml, part_o);
  hopfield_combine<<<BSZ * NHEAD, 64, 0, stream>>>(part_ml, part_o, conv,
                                                   xi_hi, xi_lo);

  // 4. readout MLP
  gemm_bias<<<dim3(DMODEL / 64, BSZ / 64), 256, 0, stream>>>(conv, Wo, bo, qe, comb, 0);
  gemm_bias<<<dim3(DMODEL / 64, BSZ / 64), 256, 0, stream>>>(comb, W1, b1, nullptr, h1, 1);
  float* rq = conv;  // conv dead after comb computed; reuse for rq
  gemm_bias<<<dim3(DMODEL / 64, BSZ / 64), 256, 0, stream>>>(h1, W2, b2, nullptr, rq, 0);

  // 5. cosine logits: split rq, then MFMA over nh with LN-reconstruction fold
  rq_prep<<<BSZ / 4, 256, 0, stream>>>(rq, rq_hi, rq_lo, rq_inv, rq_sum);
  logits_mfma<<<NTOT / 128, 256, 0, stream>>>(nh_hi, nh_lo, rq_hi, rq_lo,
                                              c1, c2, rq_inv, rq_sum, logits);

  // 6. top-4 indices
  topk_kernel<<<BSZ, 256, 0, stream>>>(logits, out);
}

// Round 9
// 1262.872 us; speedup vs baseline: 1.0906x; 1.0364x over previous
//
#include <hip/hip_runtime.h>
#include <math.h>

#define NTOT 32768
#define DMODEL 768
#define BSZ 128
#define NHEAD 16
#define DH 48
#define BETA 0.25f

typedef _Float16 f16;
typedef f16 f16x8 __attribute__((ext_vector_type(8)));
typedef f16 f16x4 __attribute__((ext_vector_type(4)));
typedef float f32x4 __attribute__((ext_vector_type(4)));

// ---------------------------------------------------------------------------
// Row stats: mean, rstd (LN, biased var, eps=1e-5), optional l2inv of raw row.
// ---------------------------------------------------------------------------
__global__ __launch_bounds__(256)
void row_stats(const float* __restrict__ X, int M, float* __restrict__ mean,
               float* __restrict__ rstd, float* __restrict__ l2inv) {
  const int row = blockIdx.x * 4 + (threadIdx.x >> 6);
  const int lane = threadIdx.x & 63;
  if (row >= M) return;
  const float* x = X + (size_t)row * DMODEL;
  float s = 0.f, s2 = 0.f;
  for (int i = lane; i < DMODEL; i += 64) {
    float v = x[i];
    s += v; s2 += v * v;
  }
#pragma unroll
  for (int off = 32; off; off >>= 1) {
    s  += __shfl_xor(s, off);
    s2 += __shfl_xor(s2, off);
  }
  if (lane == 0) {
    float mu = s * (1.f / DMODEL);
    float var = s2 * (1.f / DMODEL) - mu * mu;
    mean[row] = mu;
    rstd[row] = rsqrtf(var + 1e-5f);
    if (l2inv) l2inv[row] = 1.f / fmaxf(sqrtf(s2), 1e-12f);
  }
}

// ---------------------------------------------------------------------------
// Fused: stats over mb row + nh = (mb-mu)*rstd f16 hi/lo + logits fold consts.
// ---------------------------------------------------------------------------
__global__ __launch_bounds__(256)
void stats_norm_mb(const float* __restrict__ mb, f16* __restrict__ nh_hi,
                   f16* __restrict__ nh_lo, float* __restrict__ c1,
                   float* __restrict__ c2) {
  const int row = blockIdx.x * 4 + (threadIdx.x >> 6);
  const int lane = threadIdx.x & 63;
  const float* x = mb + (size_t)row * DMODEL;
  float v[12];
  float s = 0.f, s2 = 0.f;
#pragma unroll
  for (int j = 0; j < 3; j++) {
    const float4 v4 = *(const float4*)(x + lane * 4 + j * 256);
    v[j * 4 + 0] = v4.x; v[j * 4 + 1] = v4.y;
    v[j * 4 + 2] = v4.z; v[j * 4 + 3] = v4.w;
    s += v4.x + v4.y + v4.z + v4.w;
    s2 += v4.x * v4.x + v4.y * v4.y + v4.z * v4.z + v4.w * v4.w;
  }
#pragma unroll
  for (int off = 32; off; off >>= 1) {
    s  += __shfl_xor(s, off);
    s2 += __shfl_xor(s2, off);
  }
  const float mu = s * (1.f / DMODEL);
  const float var = s2 * (1.f / DMODEL) - mu * mu;
  const float istd = sqrtf(var + 1e-5f);
  const float rs = 1.f / istd;
  f16* oh = nh_hi + (size_t)row * DMODEL;
  f16* ol = nh_lo + (size_t)row * DMODEL;
#pragma unroll
  for (int j = 0; j < 3; j++) {
    f16x4 h4, l4;
#pragma unroll
    for (int q = 0; q < 4; q++) {
      const float sv = (v[j * 4 + q] - mu) * rs;
      const f16 h = (f16)sv;
      h4[q] = h;
      l4[q] = (f16)(sv - (float)h);
    }
    *(f16x4*)(oh + lane * 4 + j * 256) = h4;
    *(f16x4*)(ol + lane * 4 + j * 256) = l4;
  }
  if (lane == 0) {
    const float l2i = 1.f / fmaxf(sqrtf(s2), 1e-12f);
    c1[row] = 20.f * l2i * istd;
    c2[row] = 20.f * l2i * mu;
  }
}

// ---------------------------------------------------------------------------
// rq_prep: per-row sum, l2inv, and f16 hi/lo split of rq (128 rows).
// ---------------------------------------------------------------------------
__global__ __launch_bounds__(256)
void rq_prep(const float* __restrict__ rq, f16* __restrict__ hi,
             f16* __restrict__ lo, float* __restrict__ ainv,
             float* __restrict__ rqsum) {
  const int row = blockIdx.x * 4 + (threadIdx.x >> 6);
  const int lane = threadIdx.x & 63;
  const float* x = rq + (size_t)row * DMODEL;
  f16* oh = hi + (size_t)row * DMODEL;
  f16* ol = lo + (size_t)row * DMODEL;
  float s = 0.f, s2 = 0.f;
#pragma unroll
  for (int j = 0; j < 3; j++) {
    const int d = lane * 4 + j * 256;
    const float4 v4 = *(const float4*)(x + d);
    const float vv[4] = {v4.x, v4.y, v4.z, v4.w};
    f16x4 h4, l4;
#pragma unroll
    for (int q = 0; q < 4; q++) {
      s += vv[q]; s2 += vv[q] * vv[q];
      const f16 h = (f16)vv[q];
      h4[q] = h;
      l4[q] = (f16)(vv[q] - (float)h);
    }
    *(f16x4*)(oh + d) = h4;
    *(f16x4*)(ol + d) = l4;
  }
#pragma unroll
  for (int off = 32; off; off >>= 1) {
    s  += __shfl_xor(s, off);
    s2 += __shfl_xor(s2, off);
  }
  if (lane == 0) {
    rqsum[row] = s;
    ainv[row] = 1.f / fmaxf(sqrtf(s2), 1e-12f);
  }
}

// ---------------------------------------------------------------------------
// prep_w: combined W' (o<768: g_k*Wk rows; o>=768: g_v*Wv rows), scaled x16,
// split fp16 hi/lo; biasc[o] = bias[o] + sum_d bln[d]*W[o,d].
// ---------------------------------------------------------------------------
__global__ __launch_bounds__(256)
void prep_w(const float* __restrict__ Wk, const float* __restrict__ bk,
            const float* __restrict__ gk, const float* __restrict__ blnk,
            const float* __restrict__ Wv, const float* __restrict__ bv,
            const float* __restrict__ gv, const float* __restrict__ blnv,
            f16* __restrict__ Wc_hi, f16* __restrict__ Wc_lo,
            float* __restrict__ biasc) {
  const int o = blockIdx.x * 4 + (threadIdx.x >> 6);  // 0..1535
  const int lane = threadIdx.x & 63;
  const bool isK = o < DMODEL;
  const float* W = isK ? (Wk + (size_t)o * DMODEL)
                       : (Wv + (size_t)(o - DMODEL) * DMODEL);
  const float* g   = isK ? gk : gv;
  const float* bln = isK ? blnk : blnv;
  float bacc = 0.f;
  for (int d = lane * 4; d < DMODEL; d += 256) {
    const float4 wv = *(const float4*)(W + d);
    const float4 g4 = *(const float4*)(g + d);
    const float4 b4 = *(const float4*)(bln + d);
    bacc += wv.x * b4.x + wv.y * b4.y + wv.z * b4.z + wv.w * b4.w;
    const float sv[4] = {wv.x * g4.x * 16.f, wv.y * g4.y * 16.f,
                         wv.z * g4.z * 16.f, wv.w * g4.w * 16.f};
    f16x4 h4, l4;
#pragma unroll
    for (int j = 0; j < 4; j++) {
      const f16 h = (f16)sv[j];
      h4[j] = h;
      l4[j] = (f16)(sv[j] - (float)h);
    }
    *(f16x4*)(Wc_hi + (size_t)o * DMODEL + d) = h4;
    *(f16x4*)(Wc_lo + (size_t)o * DMODEL + d) = l4;
  }
#pragma unroll
  for (int off = 32; off; off >>= 1) bacc += __shfl_xor(bacc, off);
  if (lane == 0) biasc[o] = (isK ? bk[o] : bv[o - DMODEL]) + bacc;
}

// ---------------------------------------------------------------------------
// Half-projection GEMM via 16x16x32 f16 MFMA, 3-term hi/lo split.
// v2 epilogue: T (transposed) staged through LDS (reusing the dead staging
// buffers as one 128x128 f16 tile) and written as fully coalesced 256B rows.
// R8 bug fixed: k row-major store column now includes the block's o-offset
// (ob0) — R8 dropped it, clobbering k columns [0,128) from every block.
// ---------------------------------------------------------------------------
__global__ __launch_bounds__(256)
void proj_mfma(const f16* __restrict__ nh_hi, const f16* __restrict__ nh_lo,
               const f16* __restrict__ Wc_hi, const f16* __restrict__ Wc_lo,
               const float* __restrict__ biasc,
               f16* __restrict__ k_hi, f16* __restrict__ k_lo,
               f16* __restrict__ T_hi, f16* __restrict__ T_lo, int oc0) {
  __shared__ __align__(16) f16 lds[2][128][64];  // staging; reused as 128x128 tile
  f16 (&As)[128][64] = lds[0];
  f16 (&Bs)[128][64] = lds[1];
  const int t = threadIdx.x;
  const int n0 = oc0 + blockIdx.x * 128;  // global combined o base
  const int m0 = blockIdx.y * 128;
  const int w = t >> 6, lane = t & 63;
  const int l15 = lane & 15, lq = lane >> 4;
  const int wm = w >> 1, wn = w & 1;
  const int sc = (lane & 7) ^ (lane >> 3);
  const int srow = lane >> 3;

  f32x4 acc[4][4];  // [fo][fm]
#pragma unroll
  for (int a = 0; a < 4; a++)
#pragma unroll
    for (int b = 0; b < 4; b++)
#pragma unroll
      for (int r = 0; r < 4; r++) acc[a][b][r] = 0.f;

  for (int k0 = 0; k0 < DMODEL; k0 += 32) {
    __syncthreads();
#pragma unroll
    for (int i = 0; i < 4; i++) {
      const int rb = (w * 4 + i) * 8;
      const f16* asrc = ((sc < 4) ? nh_hi : nh_lo) +
          (size_t)(m0 + rb + srow) * DMODEL + k0 + (sc & 3) * 8;
      __builtin_amdgcn_global_load_lds(
          (__attribute__((address_space(1))) void*)asrc,
          (__attribute__((address_space(3))) void*)&As[rb][0], 16, 0, 0);
      const f16* bsrc = ((sc < 4) ? Wc_hi : Wc_lo) +
          (size_t)(n0 + rb + srow) * DMODEL + k0 + (sc & 3) * 8;
      __builtin_amdgcn_global_load_lds(
          (__attribute__((address_space(1))) void*)bsrc,
          (__attribute__((address_space(3))) void*)&Bs[rb][0], 16, 0, 0);
    }
    __syncthreads();

    f16x8 nhh[4], nhl[4];  // nh (B operand), free = m
#pragma unroll
    for (int fm = 0; fm < 4; fm++) {
      const int row = wm * 64 + fm * 16 + l15;
      const int e = row & 7;
      nhh[fm] = *(const f16x8*)&As[row][(lq ^ e) * 8];
      nhl[fm] = *(const f16x8*)&As[row][((lq + 4) ^ e) * 8];
    }
    f16x8 wh[4], wl[4];  // W' (A operand), free = o
#pragma unroll
    for (int fo = 0; fo < 4; fo++) {
      const int row = wn * 64 + fo * 16 + l15;
      const int e = row & 7;
      wh[fo] = *(const f16x8*)&Bs[row][(lq ^ e) * 8];
      wl[fo] = *(const f16x8*)&Bs[row][((lq + 4) ^ e) * 8];
    }
#pragma unroll
    for (int fo = 0; fo < 4; fo++)
#pragma unroll
      for (int fm = 0; fm < 4; fm++) {
        f32x4 a = acc[fo][fm];
        a = __builtin_amdgcn_mfma_f32_16x16x32_f16(wh[fo], nhh[fm], a, 0, 0, 0);
        a = __builtin_amdgcn_mfma_f32_16x16x32_f16(wh[fo], nhl[fm], a, 0, 0, 0);
        a = __builtin_amdgcn_mfma_f32_16x16x32_f16(wl[fo], nhh[fm], a, 0, 0, 0);
        acc[fo][fm] = a;
      }
  }
  // --- epilogue v2: /16, +bias, split; k rows direct, T via LDS transpose ---
  const int oc = n0 + wn * 64;           // global combined o (bias index)
  const bool wantRow = (oc0 == 0);
  const int ob0 = blockIdx.x * 128;      // block's local-o base (0..640)
  f16* tf = &lds[0][0][0];               // 128(o) x 128(m) f16 tile
  float bbv[4][4];                       // [fo][r]
#pragma unroll
  for (int fo = 0; fo < 4; fo++) {
    const float4 bb = *(const float4*)(biasc + oc + fo * 16 + lq * 4);
    bbv[fo][0] = bb.x; bbv[fo][1] = bb.y; bbv[fo][2] = bb.z; bbv[fo][3] = bb.w;
  }
  const int oloc0 = wn * 64 + lq * 4;    // lane's tile-local o base

#pragma unroll
  for (int part = 0; part < 2; part++) {
    __syncthreads();  // staging reads (part0) / prior readout (part1) complete
#pragma unroll
    for (int fo = 0; fo < 4; fo++) {
#pragma unroll
      for (int fm = 0; fm < 4; fm++) {
        const int mloc = wm * 64 + fm * 16 + l15;
        f16x4 v4;
#pragma unroll
        for (int r = 0; r < 4; r++) {
          const float v = acc[fo][fm][r] * 0.0625f + bbv[fo][r];
          const f16 h = (f16)v;
          const f16 val = part ? (f16)(v - (float)h) : h;
          v4[r] = val;
          tf[(oloc0 + fo * 16 + r) * 128 + mloc] = val;
        }
        if (wantRow) {
          const size_t moff =
              (size_t)(m0 + mloc) * DMODEL + ob0 + oloc0 + fo * 16;
          *(f16x4*)((part ? k_lo : k_hi) + moff) = v4;
        }
      }
    }
    __syncthreads();  // tile fully written
    f16* Tg = part ? T_lo : T_hi;
    const int rrow = t >> 4;         // 0..15
    const int ccol = (t & 15) * 8;   // f16 col, 16B chunks
#pragma unroll
    for (int p = 0; p < 8; p++) {
      const int row = p * 16 + rrow;
      const f16x8 vv = *(const f16x8*)&tf[row * 128 + ccol];
      *(f16x8*)(Tg + (size_t)(ob0 + row) * NTOT + m0 + ccol) = vv;
    }
  }
}

// ---------------------------------------------------------------------------
// logits via MFMA on nh: logits[b,n] = ainv[b]*(dot(nh[n],rq[b])*c1[n]
//                                              + rqsum[b]*c2[n])
// ---------------------------------------------------------------------------
__global__ __launch_bounds__(256)
void logits_mfma(const f16* __restrict__ nh_hi, const f16* __restrict__ nh_lo,
                 const f16* __restrict__ rq_hi, const f16* __restrict__ rq_lo,
                 const float* __restrict__ c1, const float* __restrict__ c2,
                 const float* __restrict__ ainv, const float* __restrict__ rqsum,
                 float* __restrict__ out) {
  __shared__ __align__(16) f16 As[128][64];  // nh tile (A operand, free=n)
  __shared__ __align__(16) f16 Bs[128][64];  // rq (B operand, free=batch)
  const int t = threadIdx.x;
  const int n0 = blockIdx.x * 128;
  const int w = t >> 6, lane = t & 63;
  const int l15 = lane & 15, lq = lane >> 4;
  const int wm = w >> 1, wn = w & 1;  // wm: batch half, wn: n half
  const int sc = (lane & 7) ^ (lane >> 3);
  const int srow = lane >> 3;

  f32x4 acc[4][4];  // [fo(n)][fm(batch)]
#pragma unroll
  for (int a = 0; a < 4; a++)
#pragma unroll
    for (int b = 0; b < 4; b++)
#pragma unroll
      for (int r = 0; r < 4; r++) acc[a][b][r] = 0.f;

  for (int k0 = 0; k0 < DMODEL; k0 += 32) {
    __syncthreads();
#pragma unroll
    for (int i = 0; i < 4; i++) {
      const int rb = (w * 4 + i) * 8;
      const f16* asrc = ((sc < 4) ? nh_hi : nh_lo) +
          (size_t)(n0 + rb + srow) * DMODEL + k0 + (sc & 3) * 8;
      __builtin_amdgcn_global_load_lds(
          (__attribute__((address_space(1))) void*)asrc,
          (__attribute__((address_space(3))) void*)&As[rb][0], 16, 0, 0);
      const f16* bsrc = ((sc < 4) ? rq_hi : rq_lo) +
          (size_t)(rb + srow) * DMODEL + k0 + (sc & 3) * 8;
      __builtin_amdgcn_global_load_lds(
          (__attribute__((address_space(1))) void*)bsrc,
          (__attribute__((address_space(3))) void*)&Bs[rb][0], 16, 0, 0);
    }
    __syncthreads();

    f16x8 ah[4], al[4];  // nh (A operand), free = n
#pragma unroll
    for (int fo = 0; fo < 4; fo++) {
      const int row = wn * 64 + fo * 16 + l15;
      const int e = row & 7;
      ah[fo] = *(const f16x8*)&As[row][(lq ^ e) * 8];
      al[fo] = *(const f16x8*)&As[row][((lq + 4) ^ e) * 8];
    }
    f16x8 bh[4], bl[4];  // rq (B operand), free = batch
#pragma unroll
    for (int fm = 0; fm < 4; fm++) {
      const int row = wm * 64 + fm * 16 + l15;
      const int e = row & 7;
      bh[fm] = *(const f16x8*)&Bs[row][(lq ^ e) * 8];
      bl[fm] = *(const f16x8*)&Bs[row][((lq + 4) ^ e) * 8];
    }
#pragma unroll
    for (int fo = 0; fo < 4; fo++)
#pragma unroll
      for (int fm = 0; fm < 4; fm++) {
        f32x4 a = acc[fo][fm];
        a = __builtin_amdgcn_mfma_f32_16x16x32_f16(ah[fo], bh[fm], a, 0, 0, 0);
        a = __builtin_amdgcn_mfma_f32_16x16x32_f16(ah[fo], bl[fm], a, 0, 0, 0);
        a = __builtin_amdgcn_mfma_f32_16x16x32_f16(al[fo], bh[fm], a, 0, 0, 0);
        acc[fo][fm] = a;
      }
  }
#pragma unroll
  for (int fm = 0; fm < 4; fm++) {
    const int b = wm * 64 + fm * 16 + l15;
    const float am = ainv[b];
    const float rs = rqsum[b];
#pragma unroll
    for (int fo = 0; fo < 4; fo++) {
      const int nb = n0 + wn * 64 + fo * 16 + lq * 4;
      const float4 c1v = *(const float4*)(c1 + nb);
      const float4 c2v = *(const float4*)(c2 + nb);
      const float c1a[4] = {c1v.x, c1v.y, c1v.z, c1v.w};
      const float c2a[4] = {c2v.x, c2v.y, c2v.z, c2v.w};
      float4 o4;
      float ov[4];
#pragma unroll
      for (int r = 0; r < 4; r++)
        ov[r] = am * (acc[fo][fm][r] * c1a[r] + rs * c2a[r]);
      o4.x = ov[0]; o4.y = ov[1]; o4.z = ov[2]; o4.w = ov[3];
      *(float4*)(out + (size_t)b * NTOT + nb) = o4;
    }
  }
}

// ---------------------------------------------------------------------------
// LN-fused GEMM, fp32 output (for q projection).
// ---------------------------------------------------------------------------
__global__ __launch_bounds__(256)
void ln_gemm_f32(const float* __restrict__ A, const float* __restrict__ mean,
                 const float* __restrict__ rstd, const float* __restrict__ g,
                 const float* __restrict__ bln, const float* __restrict__ W,
                 const float* __restrict__ bias, float* __restrict__ out) {
  __shared__ float As[16][68];
  __shared__ float Ws[16][68];
  const int t = threadIdx.x;
  const int m0 = blockIdx.y << 6, n0 = blockIdx.x << 6;
  const int tm = t >> 4, tn = t & 15;
  const int lr = t >> 2;
  const int lk = (t & 3) << 2;
  const float muL = mean[m0 + lr];
  const float rsL = rstd[m0 + lr];
  float acc[4][4] = {};
  for (int k0 = 0; k0 < DMODEL; k0 += 16) {
    float4 a4 = *(const float4*)(A + (size_t)(m0 + lr) * DMODEL + k0 + lk);
    float4 g4 = *(const float4*)(g + k0 + lk);
    float4 b4 = *(const float4*)(bln + k0 + lk);
    As[lk + 0][lr] = (a4.x - muL) * rsL * g4.x + b4.x;
    As[lk + 1][lr] = (a4.y - muL) * rsL * g4.y + b4.y;
    As[lk + 2][lr] = (a4.z - muL) * rsL * g4.z + b4.z;
    As[lk + 3][lr] = (a4.w - muL) * rsL * g4.w + b4.w;
    float4 w4 = *(const float4*)(W + (size_t)(n0 + lr) * DMODEL + k0 + lk);
    Ws[lk + 0][lr] = w4.x;
    Ws[lk + 1][lr] = w4.y;
    Ws[lk + 2][lr] = w4.z;
    Ws[lk + 3][lr] = w4.w;
    __syncthreads();
#pragma unroll
    for (int kk = 0; kk < 16; kk++) {
      const float4 av = *(const float4*)(&As[kk][tm * 4]);
      const float4 bv = *(const float4*)(&Ws[kk][tn * 4]);
      const float a[4] = {av.x, av.y, av.z, av.w};
      const float b[4] = {bv.x, bv.y, bv.z, bv.w};
#pragma unroll
      for (int i = 0; i < 4; i++)
#pragma unroll
        for (int j = 0; j < 4; j++) acc[i][j] += a[i] * b[j];
    }
    __syncthreads();
  }
  const float4 bia = *(const float4*)(bias + n0 + tn * 4);
  const float bb[4] = {bia.x, bia.y, bia.z, bia.w};
#pragma unroll
  for (int i = 0; i < 4; i++) {
    const int m = m0 + tm * 4 + i;
    float4 o4;
    o4.x = acc[i][0] + bb[0];
    o4.y = acc[i][1] + bb[1];
    o4.z = acc[i][2] + bb[2];
    o4.w = acc[i][3] + bb[3];
    *(float4*)(out + (size_t)m * DMODEL + n0 + tn * 4) = o4;
  }
}

// ---------------------------------------------------------------------------
// Plain small GEMM: out = act(A @ W^T + bias [+ add])
// ---------------------------------------------------------------------------
__global__ __launch_bounds__(256)
void gemm_bias(const float* __restrict__ A, const float* __restrict__ W,
               const float* __restrict__ bias, const float* __restrict__ add,
               float* __restrict__ out, int relu) {
  __shared__ float As[16][68];
  __shared__ float Ws[16][68];
  const int t = threadIdx.x;
  const int m0 = blockIdx.y << 6, n0 = blockIdx.x << 6;
  const int tm = t >> 4, tn = t & 15;
  const int lr = t >> 2;
  const int lk = (t & 3) << 2;
  float acc[4][4] = {};
  for (int k0 = 0; k0 < DMODEL; k0 += 16) {
    float4 a4 = *(const float4*)(A + (size_t)(m0 + lr) * DMODEL + k0 + lk);
    As[lk + 0][lr] = a4.x;
    As[lk + 1][lr] = a4.y;
    As[lk + 2][lr] = a4.z;
    As[lk + 3][lr] = a4.w;
    float4 w4 = *(const float4*)(W + (size_t)(n0 + lr) * DMODEL + k0 + lk);
    Ws[lk + 0][lr] = w4.x;
    Ws[lk + 1][lr] = w4.y;
    Ws[lk + 2][lr] = w4.z;
    Ws[lk + 3][lr] = w4.w;
    __syncthreads();
#pragma unroll
    for (int kk = 0; kk < 16; kk++) {
      const float4 av = *(const float4*)(&As[kk][tm * 4]);
      const float4 bv = *(const float4*)(&Ws[kk][tn * 4]);
      const float a[4] = {av.x, av.y, av.z, av.w};
      const float b[4] = {bv.x, bv.y, bv.z, bv.w};
#pragma unroll
      for (int i = 0; i < 4; i++)
#pragma unroll
        for (int j = 0; j < 4; j++) acc[i][j] += a[i] * b[j];
    }
    __syncthreads();
  }
  const float4 bia = *(const float4*)(bias + n0 + tn * 4);
  const float bb[4] = {bia.x, bia.y, bia.z, bia.w};
#pragma unroll
  for (int i = 0; i < 4; i++) {
    const int m = m0 + tm * 4 + i;
    float v[4];
#pragma unroll
    for (int j = 0; j < 4; j++) v[j] = acc[i][j] + bb[j];
    if (add) {
      const float4 a4 = *(const float4*)(add + (size_t)m * DMODEL + n0 + tn * 4);
      v[0] += a4.x; v[1] += a4.y; v[2] += a4.z; v[3] += a4.w;
    }
    if (relu) {
#pragma unroll
      for (int j = 0; j < 4; j++) v[j] = fmaxf(v[j], 0.f);
    }
    float4 o4 = {v[0], v[1], v[2], v[3]};
    *(float4*)(out + (size_t)m * DMODEL + n0 + tn * 4) = o4;
  }
}

// ---------------------------------------------------------------------------
// Split xi (fp32) into beta-scaled fp16 hi/lo pair. (Round-0 input only.)
// ---------------------------------------------------------------------------
__global__ __launch_bounds__(256)
void split_xi_k(const float* __restrict__ xi, f16* __restrict__ hi,
                f16* __restrict__ lo) {
  const int i = blockIdx.x * 256 + threadIdx.x;  // over float4s: 24576 total
  float4 v = ((const float4*)xi)[i];
  float s[4] = {v.x * BETA, v.y * BETA, v.z * BETA, v.w * BETA};
  f16x4 h4, l4;
#pragma unroll
  for (int j = 0; j < 4; j++) {
    f16 h = (f16)s[j];
    h4[j] = h;
    l4[j] = (f16)(s[j] - (float)h);
  }
  ((f16x4*)hi)[i] = h4;
  ((f16x4*)lo)[i] = l4;
}

// ---------------------------------------------------------------------------
// MFMA flash attention round, full hi/lo precision (fp32-accurate).
// v3+T5 (unchanged from R7).
// ---------------------------------------------------------------------------
#define FCHUNK 64
#define FROWS (NTOT / FCHUNK)  // 512

__global__ __launch_bounds__(256)
void flash_round(const f16* __restrict__ k_hi, const f16* __restrict__ k_lo,
                 const f16* __restrict__ pvT_hi, const f16* __restrict__ pvT_lo,
                 const f16* __restrict__ xi_hi, const f16* __restrict__ xi_lo,
                 float* __restrict__ part_ml, float* __restrict__ part_o) {
  const int h = blockIdx.y, chunk = blockIdx.x;
  const int tid = threadIdx.x, w = tid >> 6, lane = tid & 63;
  const int l15 = lane & 15, lq = lane >> 4;
  const int b0 = w * 32;

  __shared__ __align__(16) f16 krow[2][32][56];  // [hi/lo][n][d] (QK operand)
  __shared__ __align__(16) f16 ptT[2][48][40];   // [hi/lo][d][n] (PV operand)
  __shared__ __align__(16) f16 pHi[4][32][40];
  __shared__ __align__(16) f16 pLo[4][32][40];

  const int nbase = chunk * FROWS;

  // staging: 768 16B-chunks (krow 384 + ptT 384), thread owns cc*256+tid
  const f16* ssrc[3];
  f16* sdst[3];
  int sstep[3];
#pragma unroll
  for (int cc = 0; cc < 3; cc++) {
    const int idx = cc * 256 + tid;
    if (idx < 384) {
      const int tsel = idx / 192, q = idx % 192;
      const int r = q / 6, c = q % 6;
      ssrc[cc] = (tsel ? k_lo : k_hi) + (size_t)(nbase + r) * DMODEL + h * DH + c * 8;
      sdst[cc] = &krow[tsel][r][c * 8];
      sstep[cc] = 32 * DMODEL;
    } else {
      const int j = idx - 384;
      const int tsel = j / 192, q = j % 192;
      const int d = q / 4, c = q % 4;
      ssrc[cc] = (tsel ? pvT_lo : pvT_hi) + (size_t)(h * DH + d) * NTOT + nbase + c * 8;
      sdst[cc] = &ptT[tsel][d][c * 8];
      sstep[cc] = 32;
    }
  }

  const f16x8 zf = {};
  f16x8 xqh[2][2], xql[2][2];
#pragma unroll
  for (int bt = 0; bt < 2; bt++) {
    const size_t xoff = (size_t)(b0 + bt * 16 + l15) * DMODEL + h * DH;
    xqh[bt][0] = *(const f16x8*)(xi_hi + xoff + lq * 8);
    xql[bt][0] = *(const f16x8*)(xi_lo + xoff + lq * 8);
    const size_t xo1 = xoff + 32 + (lq & 1) * 8;
    f16x8 th = *(const f16x8*)(xi_hi + xo1);
    f16x8 tl = *(const f16x8*)(xi_lo + xo1);
    xqh[bt][1] = (lq < 2) ? th : zf;
    xql[bt][1] = (lq < 2) ? tl : zf;
  }

  float m[2] = {-1e30f, -1e30f}, lsum[2] = {0.f, 0.f};
  f32x4 O[3][2];
#pragma unroll
  for (int mt = 0; mt < 3; mt++)
#pragma unroll
    for (int bt = 0; bt < 2; bt++)
#pragma unroll
      for (int j = 0; j < 4; j++) O[mt][bt][j] = 0.f;

  // prologue: stage tile 0
  f16x8 stg[3];
#pragma unroll
  for (int cc = 0; cc < 3; cc++) {
    stg[cc] = *(const f16x8*)ssrc[cc];
    ssrc[cc] += sstep[cc];
  }
#pragma unroll
  for (int cc = 0; cc < 3; cc++) *(f16x8*)sdst[cc] = stg[cc];
  __syncthreads();

  for (int it = 0; it < 16; it++) {
    // T14: issue next tile's global loads before compute
    if (it < 15) {
#pragma unroll
      for (int cc = 0; cc < 3; cc++) {
        stg[cc] = *(const f16x8*)ssrc[cc];
        ssrc[cc] += sstep[cc];
      }
    }

    f16x8 akh[2][2], akl[2][2];
#pragma unroll
    for (int nt = 0; nt < 2; nt++) {
      const int row = nt * 16 + l15;
      akh[nt][0] = *(const f16x8*)&krow[0][row][lq * 8];
      akl[nt][0] = *(const f16x8*)&krow[1][row][lq * 8];
      f16x8 t0 = *(const f16x8*)&krow[0][row][32 + (lq & 1) * 8];
      f16x8 t1 = *(const f16x8*)&krow[1][row][32 + (lq & 1) * 8];
      akh[nt][1] = (lq < 2) ? t0 : zf;
      akl[nt][1] = (lq < 2) ? t1 : zf;
    }
    f32x4 S[2][2];
    __builtin_amdgcn_s_setprio(1);
#pragma unroll
    for (int nt = 0; nt < 2; nt++)
#pragma unroll
      for (int bt = 0; bt < 2; bt++) {
        f32x4 s = {};
        s = __builtin_amdgcn_mfma_f32_16x16x32_f16(akh[nt][0], xqh[bt][0], s, 0, 0, 0);
        s = __builtin_amdgcn_mfma_f32_16x16x32_f16(akh[nt][1], xqh[bt][1], s, 0, 0, 0);
        s = __builtin_amdgcn_mfma_f32_16x16x32_f16(akh[nt][0], xql[bt][0], s, 0, 0, 0);
        s = __builtin_amdgcn_mfma_f32_16x16x32_f16(akh[nt][1], xql[bt][1], s, 0, 0, 0);
        s = __builtin_amdgcn_mfma_f32_16x16x32_f16(akl[nt][0], xqh[bt][0], s, 0, 0, 0);
        s = __builtin_amdgcn_mfma_f32_16x16x32_f16(akl[nt][1], xqh[bt][1], s, 0, 0, 0);
        S[nt][bt] = s;
      }
    __builtin_amdgcn_s_setprio(0);
    float sc[2];
#pragma unroll
    for (int bt = 0; bt < 2; bt++) {
      float mx = S[0][bt][0];
#pragma unroll
      for (int r = 1; r < 4; r++) mx = fmaxf(mx, S[0][bt][r]);
#pragma unroll
      for (int r = 0; r < 4; r++) mx = fmaxf(mx, S[1][bt][r]);
      mx = fmaxf(mx, __shfl_xor(mx, 16));
      mx = fmaxf(mx, __shfl_xor(mx, 32));
      const float mnew = fmaxf(m[bt], mx);
      sc[bt] = __expf(m[bt] - mnew);
      float ps = 0.f;
#pragma unroll
      for (int nt = 0; nt < 2; nt++) {
        f16x4 ph, pl;
#pragma unroll
        for (int r = 0; r < 4; r++) {
          const float p = __expf(S[nt][bt][r] - mnew);
          ps += p;
          const f16 hh = (f16)p;
          ph[r] = hh;
          pl[r] = (f16)(p - (float)hh);
        }
        *(f16x4*)&pHi[w][bt * 16 + l15][nt * 16 + lq * 4] = ph;
        *(f16x4*)&pLo[w][bt * 16 + l15][nt * 16 + lq * 4] = pl;
      }
      ps += __shfl_xor(ps, 16);
      ps += __shfl_xor(ps, 32);
      lsum[bt] = lsum[bt] * sc[bt] + ps;
      m[bt] = mnew;
    }
    __asm__ volatile("s_waitcnt lgkmcnt(0)" ::: "memory");
    f16x8 avh[3], avl[3];
#pragma unroll
    for (int mt = 0; mt < 3; mt++) {
      avh[mt] = *(const f16x8*)&ptT[0][mt * 16 + l15][lq * 8];
      avl[mt] = *(const f16x8*)&ptT[1][mt * 16 + l15][lq * 8];
    }
    f16x8 pbh[2], pbl[2];
#pragma unroll
    for (int bt = 0; bt < 2; bt++) {
      pbh[bt] = *(const f16x8*)&pHi[w][bt * 16 + l15][lq * 8];
      pbl[bt] = *(const f16x8*)&pLo[w][bt * 16 + l15][lq * 8];
    }
    __builtin_amdgcn_s_setprio(1);
#pragma unroll
    for (int mt = 0; mt < 3; mt++)
#pragma unroll
      for (int bt = 0; bt < 2; bt++) {
#pragma unroll
        for (int j = 0; j < 4; j++) O[mt][bt][j] *= sc[bt];
        f32x4 o = O[mt][bt];
        o = __builtin_amdgcn_mfma_f32_16x16x32_f16(avh[mt], pbh[bt], o, 0, 0, 0);
        o = __builtin_amdgcn_mfma_f32_16x16x32_f16(avh[mt], pbl[bt], o, 0, 0, 0);
        o = __builtin_amdgcn_mfma_f32_16x16x32_f16(avl[mt], pbh[bt], o, 0, 0, 0);
        O[mt][bt] = o;
      }
    __builtin_amdgcn_s_setprio(0);

    // T14 tail: all waves done reading this tile -> overwrite with next
    if (it < 15) {
      __syncthreads();
#pragma unroll
      for (int cc = 0; cc < 3; cc++) *(f16x8*)sdst[cc] = stg[cc];
      __syncthreads();
    }
  }
  const int pc = h * FCHUNK + chunk;
  if (lq == 0) {
#pragma unroll
    for (int bt = 0; bt < 2; bt++) {
      float* pm = part_ml + ((size_t)pc * BSZ + b0 + bt * 16 + l15) * 2;
      pm[0] = m[bt];
      pm[1] = lsum[bt];
    }
  }
#pragma unroll
  for (int mt = 0; mt < 3; mt++)
#pragma unroll
    for (int bt = 0; bt < 2; bt++) {
      float* po = part_o + ((size_t)pc * BSZ + b0 + bt * 16 + l15) * 48 +
                  mt * 16 + lq * 4;
      *(f32x4*)po = O[mt][bt];
    }
}

// ---------------------------------------------------------------------------
// Combine 64 chunk-partials per (b,h) AND emit the beta-scaled f16 hi/lo
// split of the result. Grid = B*H blocks of 64 threads.
// ---------------------------------------------------------------------------
__global__ __launch_bounds__(64)
void hopfield_combine(const float* __restrict__ part_ml,
                      const float* __restrict__ part_o, float* __restrict__ dst,
                      f16* __restrict__ nx_hi, f16* __restrict__ nx_lo) {
  const int bh = blockIdx.x;  // h*128 + b
  const int h = bh >> 7, b = bh & 127;
  const int c = threadIdx.x;
  __shared__ float w[64];
  const float* pm = part_ml + ((size_t)(h * 64 + c) * BSZ + b) * 2;
  const float mp = pm[0];
  const float lp = pm[1];
  float M = mp;
#pragma unroll
  for (int off = 32; off; off >>= 1) M = fmaxf(M, __shfl_xor(M, off));
  const float wp = __expf(mp - M);
  w[c] = wp;
  float L = lp * wp;
#pragma unroll
  for (int off = 32; off; off >>= 1) L += __shfl_xor(L, off);
  __syncthreads();
  if (c < DH) {
    float o = 0.f;
    for (int p = 0; p < 64; p++)
      o += part_o[((size_t)(h * 64 + p) * BSZ + b) * 48 + c] * w[p];
    const float val = o / L;
    const size_t di = (size_t)b * DMODEL + h * DH + c;
    dst[di] = val;
    const float s = val * BETA;
    const f16 hh = (f16)s;
    nx_hi[di] = hh;
    nx_lo[di] = (f16)(s - (float)hh);
  }
}

// ---------------------------------------------------------------------------
// Top-4 per row with jax tie-breaking (lower index first).
// ---------------------------------------------------------------------------
__global__ __launch_bounds__(256)
void topk_kernel(const float* __restrict__ logits, float* __restrict__ outIdx) {
  const int b = blockIdx.x;
  const int t = threadIdx.x;
  const float* row = logits + (size_t)b * NTOT;
  float v[4] = {-1e30f, -1e30f, -1e30f, -1e30f};
  int id[4] = {0x7fffffff, 0x7fffffff, 0x7fffffff, 0x7fffffff};
  for (int n = t; n < NTOT; n += 256) {
    const float x = row[n];
    if (x > v[3]) {
      v[3] = x; id[3] = n;
#pragma unroll
      for (int s = 3; s > 0; s--) {
        const bool sw = (v[s] > v[s - 1]) || (v[s] == v[s - 1] && id[s] < id[s - 1]);
        if (sw) {
          float tv = v[s]; v[s] = v[s - 1]; v[s - 1] = tv;
          int ti = id[s]; id[s] = id[s - 1]; id[s - 1] = ti;
        }
      }
    }
  }
  __shared__ float sv[256][4];
  __shared__ int si[256][4];
#pragma unroll
  for (int j = 0; j < 4; j++) { sv[t][j] = v[j]; si[t][j] = id[j]; }
  for (int str = 128; str >= 1; str >>= 1) {
    __syncthreads();
    if (t < str) {
      float a[4], c[4];
      int ai[4], ci[4];
#pragma unroll
      for (int j = 0; j < 4; j++) {
        a[j] = sv[t][j]; ai[j] = si[t][j];
        c[j] = sv[t + str][j]; ci[j] = si[t + str][j];
      }
      float rv[4]; int ri[4];
      int p = 0, q = 0;
#pragma unroll
      for (int oo = 0; oo < 4; oo++) {
        const bool ta = (a[p] > c[q]) || (a[p] == c[q] && ai[p] < ci[q]);
        if (ta) { rv[oo] = a[p]; ri[oo] = ai[p]; p++; }
        else    { rv[oo] = c[q]; ri[oo] = ci[q]; q++; }
      }
#pragma unroll
      for (int j = 0; j < 4; j++) { sv[t][j] = rv[j]; si[t][j] = ri[j]; }
    }
  }
  if (t == 0) {
#pragma unroll
    for (int j = 0; j < 4; j++) outIdx[b * 4 + j] = (float)si[0][j];
  }
}

// ---------------------------------------------------------------------------
extern "C" void kernel_launch(void* const* d_in, const int* in_sizes, int n_in,
                              void* d_out, int out_size, void* d_ws, size_t ws_size,
                              hipStream_t stream) {
  const float* qe    = (const float*)d_in[0];
  const float* mb    = (const float*)d_in[1];
  const float* ln_kg = (const float*)d_in[2];
  const float* ln_kb = (const float*)d_in[3];
  const float* ln_qg = (const float*)d_in[4];
  const float* ln_qb = (const float*)d_in[5];
  const float* ln_vg = (const float*)d_in[6];
  const float* ln_vb = (const float*)d_in[7];
  const float* Wq = (const float*)d_in[8];
  const float* bq = (const float*)d_in[9];
  const float* Wk = (const float*)d_in[10];
  const float* bk = (const float*)d_in[11];
  const float* Wv = (const float*)d_in[12];
  const float* bv = (const float*)d_in[13];
  const float* Wo = (const float*)d_in[14];
  const float* bo = (const float*)d_in[15];
  const float* W1 = (const float*)d_in[16];
  const float* b1 = (const float*)d_in[17];
  const float* W2 = (const float*)d_in[18];
  const float* b2 = (const float*)d_in[19];

  float* out = (float*)d_out;  // [0..511] top indices (as float), then logits
  float* logits = out + BSZ * 4;

  float* ws = (float*)d_ws;
  size_t off = 0;
  auto alloc = [&](size_t n) { float* p = ws + off; off += n; return p; };
  const size_t ND2 = (size_t)NTOT * DMODEL / 2;  // one fp16 N*D buffer, in floats
  float* c1      = alloc(NTOT);
  float* c2      = alloc(NTOT);
  float* q_mean  = alloc(128);
  float* q_rstd  = alloc(128);
  float* rq_inv  = alloc(128);
  float* rq_sum  = alloc(128);
  float* pad_    = alloc(256);
  f16* k_hi  = (f16*)alloc(ND2);  // [N][768] row-major (QK operand)
  f16* k_lo  = (f16*)alloc(ND2);
  f16* T_hi  = (f16*)alloc(ND2);  // [768][N]: K^T for rounds 0-4, then V^T
  f16* T_lo  = (f16*)alloc(ND2);
  f16* nh_hi = (f16*)alloc(ND2);  // normalized mb, fp16 hi/lo
  f16* nh_lo = (f16*)alloc(ND2);
  float* part_ml = alloc((size_t)NHEAD * FCHUNK * BSZ * 2);
  float* part_o  = alloc((size_t)NHEAD * FCHUNK * BSZ * 48);
  float* xi   = alloc((size_t)BSZ * DMODEL);
  float* conv = alloc((size_t)BSZ * DMODEL);
  float* comb = alloc((size_t)BSZ * DMODEL);
  float* h1   = alloc((size_t)BSZ * DMODEL);
  f16* xi_hi = (f16*)alloc((size_t)BSZ * DMODEL / 2);
  f16* xi_lo = (f16*)alloc((size_t)BSZ * DMODEL / 2);
  f16* rq_hi = (f16*)alloc((size_t)BSZ * DMODEL / 2);
  f16* rq_lo = (f16*)alloc((size_t)BSZ * DMODEL / 2);
  f16* Wc_hi = (f16*)alloc((size_t)2 * DMODEL * DMODEL / 2);  // [1536][768]
  f16* Wc_lo = (f16*)alloc((size_t)2 * DMODEL * DMODEL / 2);
  float* biasc = alloc(2 * DMODEL);
  (void)ws_size; (void)in_sizes; (void)n_in; (void)out_size; (void)pad_;

  // 1. stats (q) + fused stats/normalize/split (mb) + W prep
  row_stats<<<BSZ / 4, 256, 0, stream>>>(qe, BSZ, q_mean, q_rstd, nullptr);
  stats_norm_mb<<<NTOT / 4, 256, 0, stream>>>(mb, nh_hi, nh_lo, c1, c2);
  prep_w<<<2 * DMODEL / 4, 256, 0, stream>>>(Wk, bk, ln_kg, ln_kb,
                                             Wv, bv, ln_vg, ln_vb,
                                             Wc_hi, Wc_lo, biasc);

  // 2. K-half projection (k row-major + K^T into T); q (xi) fp32
  proj_mfma<<<dim3(DMODEL / 128, NTOT / 128), 256, 0, stream>>>(
      nh_hi, nh_lo, Wc_hi, Wc_lo, biasc, k_hi, k_lo, T_hi, T_lo, 0);
  ln_gemm_f32<<<dim3(DMODEL / 64, BSZ / 64), 256, 0, stream>>>(
      qe, q_mean, q_rstd, ln_qg, ln_qb, Wq, bq, xi);

  // 3. Hopfield rounds 0-4 (PV source = K^T in T); split fused into combine
  split_xi_k<<<96, 256, 0, stream>>>(xi, xi_hi, xi_lo);
  for (int r = 0; r < 5; r++) {
    flash_round<<<dim3(FCHUNK, NHEAD), 256, 0, stream>>>(
        k_hi, k_lo, T_hi, T_lo, xi_hi, xi_lo, part_ml, part_o);
    hopfield_combine<<<BSZ * NHEAD, 64, 0, stream>>>(part_ml, part_o, xi,
                                                     xi_hi, xi_lo);
  }

  // 3b. V-half projection: writes V^T over the (now dead) K^T buffer
  proj_mfma<<<dim3(DMODEL / 128, NTOT / 128), 256, 0, stream>>>(
      nh_hi, nh_lo, Wc_hi, Wc_lo, biasc, k_hi, k_lo, T_hi, T_lo, DMODEL);

  // 3c. readout round (PV source = V^T in T); xi split comes from round 4
  flash_round<<<dim3(FCHUNK, NHEAD), 256, 0, stream>>>(
      k_hi, k_lo, T_hi, T_lo, xi_hi, xi_lo, part_ml, part_o);
  hopfield_combine<<<BSZ * NHEAD, 64, 0, stream>>>(part_ml, part_o, conv,
                                                   xi_hi, xi_lo);

  // 4. readout MLP
  gemm_bias<<<dim3(DMODEL / 64, BSZ / 64), 256, 0, stream>>>(conv, Wo, bo, qe, comb, 0);
  gemm_bias<<<dim3(DMODEL / 64, BSZ / 64), 256, 0, stream>>>(comb, W1, b1, nullptr, h1, 1);
  float* rq = conv;  // conv dead after comb computed; reuse for rq
  gemm_bias<<<dim3(DMODEL / 64, BSZ / 64), 256, 0, stream>>>(h1, W2, b2, nullptr, rq, 0);

  // 5. cosine logits: split rq, then MFMA over nh with LN-reconstruction fold
  rq_prep<<<BSZ / 4, 256, 0, stream>>>(rq, rq_hi, rq_lo, rq_inv, rq_sum);
  logits_mfma<<<NTOT / 128, 256, 0, stream>>>(nh_hi, nh_lo, rq_hi, rq_lo,
                                              c1, c2, rq_inv, rq_sum, logits);

  // 6. top-4 indices
  topk_kernel<<<BSZ, 256, 0, stream>>>(logits, out);
}